// Round 13
// baseline (602.579 us; speedup 1.0000x reference)
//
#include <hip/hip_runtime.h>
#include <hip/hip_bf16.h>
#include <math.h>

#define EPS_ 1e-5f
constexpr int B_ = 4, NA = 64, T_ = 128, D_ = 128, H_ = 8, L_ = 3, DFF = 512, E_ = 65536;
constexpr int DH = D_ / H_;        // 16
constexpr int NN = T_ * NA;        // 8192
constexpr int NTOT = B_ * NA * T_; // 32768
constexpr int QLD = 384;           // packed QKV row stride
constexpr size_t NE_ = (size_t)NTOT * D_;

typedef __bf16 bf16x8 __attribute__((ext_vector_type(8)));
typedef float f32x4 __attribute__((ext_vector_type(4)));

// ---------------- embed: x = hist@W + b ; e = x + posenc ----------------
__global__ __launch_bounds__(256) void embed_kernel(
    const float* __restrict__ hist, const float* __restrict__ w,
    const float* __restrict__ b, float* __restrict__ x, float* __restrict__ e) {
  int idx = blockIdx.x * 256 + threadIdx.x;
  if (idx >= NTOT * D_) return;
  int d = idx & (D_ - 1);
  int r = idx >> 7;
  int t = r & (T_ - 1);
  const float* hp = hist + (size_t)r * 3;
  float acc = b[d];
  acc += hp[0] * w[0 * D_ + d];
  acc += hp[1] * w[1 * D_ + d];
  acc += hp[2] * w[2 * D_ + d];
  x[idx] = acc;
  int p = d >> 1;
  float ang = (float)t * expf(-logf(10000.f) * (2.f * (float)p) / (float)D_);
  float pe = (d & 1) ? cosf(ang) : sinf(ang);
  e[idx] = acc + pe;
}

// ---------------- weight split into FRAGMENT-LINEAR bf16 hi/lo ----------------
__global__ __launch_bounds__(256) void convert_weights(
    const float* __restrict__ wq, const float* __restrict__ wk,
    const float* __restrict__ wv, const float* __restrict__ wo,
    const float* __restrict__ w1, const float* __restrict__ w2,
    __bf16* __restrict__ hi, __bf16* __restrict__ lo) {
  const int LW = 196608;
  int idx = blockIdx.x * 256 + threadIdx.x;
  if (idx >= L_ * LW) return;
  int l = idx / LW;
  int rem = idx - l * LW;
  float src;
  int n, k, K, segoff;
  if (rem < 49152) { // qkv
    n = rem >> 7; k = rem & 127; K = 128; segoff = 0;
    int which = n >> 7, nl = n & 127;
    const float* W = (which == 0) ? wq : (which == 1) ? wk : wv;
    src = W[(size_t)l * 16384 + k * 128 + nl];
  } else if (rem < 65536) { // wo
    int r2 = rem - 49152;
    n = r2 >> 7; k = r2 & 127; K = 128; segoff = 49152;
    src = wo[(size_t)l * 16384 + k * 128 + n];
  } else if (rem < 131072) { // w1
    int r2 = rem - 65536;
    n = r2 >> 7; k = r2 & 127; K = 128; segoff = 65536;
    src = w1[(size_t)l * 65536 + k * 512 + n];
  } else { // w2
    int r2 = rem - 131072;
    n = r2 >> 9; k = r2 & 511; K = 512; segoff = 131072;
    src = w2[(size_t)l * 65536 + k * 128 + n];
  }
  int nt = n >> 4, kt = k >> 5;
  int lane = ((k >> 3) & 3) * 16 + (n & 15);
  int j = k & 7;
  int dst = l * LW + segoff + ((nt * (K / 32) + kt) * 64 + lane) * 8 + j;
  __bf16 h = (__bf16)src;
  hi[dst] = h;
  lo[dst] = (__bf16)(src - (float)h);
}

// ---------------- pack QKV biases ----------------
__global__ __launch_bounds__(256) void bias_pack(
    const float* __restrict__ bq, const float* __restrict__ bk,
    const float* __restrict__ bv, float* __restrict__ pb) {
  int idx = blockIdx.x * 256 + threadIdx.x;
  if (idx >= L_ * QLD) return;
  int l = idx / QLD, n = idx - l * QLD;
  int which = n >> 7, nl = n & 127;
  const float* src = (which == 0) ? bq : (which == 1) ? bk : bv;
  pb[idx] = src[l * 128 + nl];
}

__device__ __forceinline__ void split8(const float* __restrict__ p,
                                       bf16x8& hi, bf16x8& lo) {
  float4 x0 = *(const float4*)p;
  float4 x1 = *(const float4*)(p + 4);
  float xv[8] = {x0.x, x0.y, x0.z, x0.w, x1.x, x1.y, x1.z, x1.w};
#pragma unroll
  for (int j = 0; j < 8; ++j) {
    __bf16 h = (__bf16)xv[j];
    hi[j] = h;
    lo[j] = (__bf16)(xv[j] - (float)h);
  }
}

// ---------------- Unified staged MFMA GEMM: block 64 rows x 128 cols ----------------
// A staged per 128-K chunk into LDS (coalesced), frag-linear B, hi/lo fp32-grade.
// EPI: 0=bias, 1=bias+relu, 2=bias+resid+LayerNorm (needs total N==128, grid.x==1).
// grid = (N/128, M/64).
template <int EPI, int K>
__global__ __launch_bounds__(256) void gemm_s(
    const float* __restrict__ A, int lda,
    const __bf16* __restrict__ Whi, const __bf16* __restrict__ Wlo,
    const float* __restrict__ bias, const float* __restrict__ resid,
    const float* __restrict__ lng, const float* __restrict__ lnb,
    float* __restrict__ C, int ldc) {
  const int wave = threadIdx.x >> 6;
  const int lane = threadIdx.x & 63;
  const int m16 = lane & 15;
  const int quad = lane >> 4;
  const int wrow = wave >> 1, wcol = wave & 1;
  const int grow0 = blockIdx.y * 64;
  const int lrow0 = wrow * 32;
  const int col0 = blockIdx.x * 128 + wcol * 64;
  const int ctb = (blockIdx.x * 8) + wcol * 4; // n-tile base

  __shared__ float As[64][129]; // 33 KB; stride 129 -> linear bank spread

  f32x4 acc[2][4] = {};
#pragma unroll
  for (int kc = 0; kc < K / 128; ++kc) {
    if (kc) __syncthreads();
    // stage A chunk: 64 rows x 128 floats, coalesced float4 bursts
#pragma unroll
    for (int u = 0; u < 8; ++u) {
      int unit = threadIdx.x + u * 256; // 2048 float4 units
      int r = unit >> 5, c4 = unit & 31;
      float4 v = *(const float4*)(A + (size_t)(grow0 + r) * lda + kc * 128 + c4 * 4);
      As[r][c4 * 4 + 0] = v.x;
      As[r][c4 * 4 + 1] = v.y;
      As[r][c4 * 4 + 2] = v.z;
      As[r][c4 * 4 + 3] = v.w;
    }
    __syncthreads();
#pragma unroll
    for (int kt = 0; kt < 4; ++kt) {
      bf16x8 ahi[2], alo[2];
#pragma unroll
      for (int mf = 0; mf < 2; ++mf)
        split8(&As[lrow0 + mf * 16 + m16][kt * 32 + quad * 8], ahi[mf], alo[mf]);
      bf16x8 bhi[4], blo[4];
#pragma unroll
      for (int nf = 0; nf < 4; ++nf) {
        size_t off = ((size_t)(ctb + nf) * (K / 32) + (kc * 4 + kt)) * 512 + lane * 8;
        bhi[nf] = *(const bf16x8*)(Whi + off);
        blo[nf] = *(const bf16x8*)(Wlo + off);
      }
#pragma unroll
      for (int mf = 0; mf < 2; ++mf)
#pragma unroll
        for (int nf = 0; nf < 4; ++nf) {
          acc[mf][nf] = __builtin_amdgcn_mfma_f32_16x16x32_bf16(ahi[mf], bhi[nf], acc[mf][nf], 0, 0, 0);
          acc[mf][nf] = __builtin_amdgcn_mfma_f32_16x16x32_bf16(ahi[mf], blo[nf], acc[mf][nf], 0, 0, 0);
          acc[mf][nf] = __builtin_amdgcn_mfma_f32_16x16x32_bf16(alo[mf], bhi[nf], acc[mf][nf], 0, 0, 0);
        }
    }
  }

  if (EPI < 2) {
#pragma unroll
    for (int mf = 0; mf < 2; ++mf)
#pragma unroll
      for (int nf = 0; nf < 4; ++nf) {
        int c = col0 + nf * 16 + m16;
        float bj = bias[c];
#pragma unroll
        for (int reg = 0; reg < 4; ++reg) {
          int r = grow0 + lrow0 + mf * 16 + quad * 4 + reg;
          float v = acc[mf][nf][reg] + bj;
          if (EPI == 1) v = fmaxf(v, 0.f);
          C[(size_t)r * ldc + c] = v;
        }
      }
  } else {
    __shared__ float rs[64][2], rq[64][2];
#pragma unroll
    for (int mf = 0; mf < 2; ++mf)
#pragma unroll
      for (int reg = 0; reg < 4; ++reg) {
        int lr = lrow0 + mf * 16 + quad * 4 + reg;
        int gr = grow0 + lr;
        float s = 0.f, qq = 0.f;
#pragma unroll
        for (int nf = 0; nf < 4; ++nf) {
          int c = wcol * 64 + nf * 16 + m16;
          float v = acc[mf][nf][reg] + bias[c] + resid[(size_t)gr * 128 + c];
          acc[mf][nf][reg] = v;
          s += v;
          qq += v * v;
        }
#pragma unroll
        for (int off = 1; off < 16; off <<= 1) {
          s += __shfl_xor(s, off, 64);
          qq += __shfl_xor(qq, off, 64);
        }
        if (m16 == 0) { rs[lr][wcol] = s; rq[lr][wcol] = qq; }
      }
    __syncthreads();
#pragma unroll
    for (int mf = 0; mf < 2; ++mf)
#pragma unroll
      for (int reg = 0; reg < 4; ++reg) {
        int lr = lrow0 + mf * 16 + quad * 4 + reg;
        int gr = grow0 + lr;
        float mean = (rs[lr][0] + rs[lr][1]) * (1.f / 128.f);
        float var = (rq[lr][0] + rq[lr][1]) * (1.f / 128.f) - mean * mean;
        float rstd = rsqrtf(var + EPS_);
#pragma unroll
        for (int nf = 0; nf < 4; ++nf) {
          int c = wcol * 64 + nf * 16 + m16;
          C[(size_t)gr * 128 + c] = (acc[mf][nf][reg] - mean) * rstd * lng[c] + lnb[c];
        }
      }
  }
}

// ---------------- MFMA attention on packed QKV; O overwrites the V slice ----------------
__global__ __launch_bounds__(256) void attn_mfma(float* __restrict__ qkv) {
  const int h = blockIdx.x & (H_ - 1);
  const int bn = blockIdx.x >> 3;
  const int wave = threadIdx.x >> 6;
  const int lane = threadIdx.x & 63;
  const int m16 = lane & 15;
  const int quad = lane >> 4;
  const int row0 = wave * 32;
  const float* Qb = qkv + (size_t)bn * T_ * QLD + h * DH;
  const float* Kb = Qb + 128;
  const float* Vb = Qb + 256;
  float* Ob = (float*)Vb;

  __shared__ __bf16 Plds[4][32][136];

  bf16x8 qhi[2], qlo[2];
#pragma unroll
  for (int mf = 0; mf < 2; ++mf) {
    if (quad < 2) {
      split8(Qb + (size_t)(row0 + mf * 16 + m16) * QLD + quad * 8, qhi[mf], qlo[mf]);
    } else {
#pragma unroll
      for (int j = 0; j < 8; ++j) { qhi[mf][j] = (__bf16)0.f; qlo[mf][j] = (__bf16)0.f; }
    }
  }

  f32x4 acc[2][8] = {};
#pragma unroll
  for (int nf = 0; nf < 8; ++nf) {
    bf16x8 khi, klo;
    if (quad < 2) {
      split8(Kb + (size_t)(nf * 16 + m16) * QLD + quad * 8, khi, klo);
    } else {
#pragma unroll
      for (int j = 0; j < 8; ++j) { khi[j] = (__bf16)0.f; klo[j] = (__bf16)0.f; }
    }
#pragma unroll
    for (int mf = 0; mf < 2; ++mf) {
      acc[mf][nf] = __builtin_amdgcn_mfma_f32_16x16x32_bf16(qhi[mf], khi, acc[mf][nf], 0, 0, 0);
      acc[mf][nf] = __builtin_amdgcn_mfma_f32_16x16x32_bf16(qhi[mf], klo, acc[mf][nf], 0, 0, 0);
      acc[mf][nf] = __builtin_amdgcn_mfma_f32_16x16x32_bf16(qlo[mf], khi, acc[mf][nf], 0, 0, 0);
    }
  }

  const float scale = 0.25f;
#pragma unroll
  for (int mf = 0; mf < 2; ++mf)
#pragma unroll
    for (int reg = 0; reg < 4; ++reg) {
      float mx = -1e30f;
#pragma unroll
      for (int nf = 0; nf < 8; ++nf) mx = fmaxf(mx, acc[mf][nf][reg]);
#pragma unroll
      for (int off = 1; off < 16; off <<= 1) mx = fmaxf(mx, __shfl_xor(mx, off, 64));
      float sum = 0.f;
#pragma unroll
      for (int nf = 0; nf < 8; ++nf) {
        float e = __expf((acc[mf][nf][reg] - mx) * scale);
        acc[mf][nf][reg] = e;
        sum += e;
      }
#pragma unroll
      for (int off = 1; off < 16; off <<= 1) sum += __shfl_xor(sum, off, 64);
      float inv = 1.f / sum;
#pragma unroll
      for (int nf = 0; nf < 8; ++nf) acc[mf][nf][reg] *= inv;
    }

#pragma unroll
  for (int mf = 0; mf < 2; ++mf)
#pragma unroll
    for (int nf = 0; nf < 8; ++nf)
#pragma unroll
      for (int reg = 0; reg < 4; ++reg)
        Plds[wave][mf * 16 + quad * 4 + reg][nf * 16 + m16] = (__bf16)acc[mf][nf][reg];

  f32x4 oacc[2] = {};
#pragma unroll
  for (int kc = 0; kc < 4; ++kc) {
    bf16x8 pa0 = *(const bf16x8*)&Plds[wave][m16][kc * 32 + quad * 8];
    bf16x8 pa1 = *(const bf16x8*)&Plds[wave][16 + m16][kc * 32 + quad * 8];
    bf16x8 vhi, vlo;
#pragma unroll
    for (int j = 0; j < 8; ++j) {
      float x = Vb[(size_t)(kc * 32 + quad * 8 + j) * QLD + m16];
      __bf16 hh = (__bf16)x;
      vhi[j] = hh;
      vlo[j] = (__bf16)(x - (float)hh);
    }
    oacc[0] = __builtin_amdgcn_mfma_f32_16x16x32_bf16(pa0, vhi, oacc[0], 0, 0, 0);
    oacc[0] = __builtin_amdgcn_mfma_f32_16x16x32_bf16(pa0, vlo, oacc[0], 0, 0, 0);
    oacc[1] = __builtin_amdgcn_mfma_f32_16x16x32_bf16(pa1, vhi, oacc[1], 0, 0, 0);
    oacc[1] = __builtin_amdgcn_mfma_f32_16x16x32_bf16(pa1, vlo, oacc[1], 0, 0, 0);
  }

  __syncthreads();
#pragma unroll
  for (int mf = 0; mf < 2; ++mf)
#pragma unroll
    for (int reg = 0; reg < 4; ++reg) {
      int r = row0 + mf * 16 + quad * 4 + reg;
      Ob[(size_t)r * QLD + m16] = oacc[mf][reg];
    }
}

// ---------------- gating dot ----------------
__global__ __launch_bounds__(256) void sdot_kernel(
    const float* __restrict__ e, const float* __restrict__ x, float* __restrict__ s) {
  int r = blockIdx.x * 4 + (threadIdx.x >> 6);
  int lane = threadIdx.x & 63;
  const float* ep = e + (size_t)r * D_;
  const float* xp = x + (size_t)r * D_;
  float acc = ep[lane] * xp[lane] + ep[lane + 64] * xp[lane + 64];
#pragma unroll
  for (int off = 32; off; off >>= 1) acc += __shfl_down(acc, off, 64);
  if (lane == 0) {
    int t = r & (T_ - 1);
    int bn = r >> 7;
    int n = bn & (NA - 1);
    int b = bn >> 6;
    s[(size_t)b * NN + t * NA + n] = acc;
  }
}

// ---------------- edge scatter ----------------
__global__ __launch_bounds__(256) void scatter_kernel(
    const float* __restrict__ s, const int* __restrict__ ei,
    const float* __restrict__ ew, float* __restrict__ g) {
  int idx = blockIdx.x * 256 + threadIdx.x;
  if (idx >= B_ * E_) return;
  int b = idx >> 16;
  int e = idx & (E_ - 1);
  int src = ei[(size_t)b * 2 * E_ + e];
  int dst = ei[(size_t)b * 2 * E_ + E_ + e];
  float w = ew[(size_t)b * E_ + e];
  atomicAdd(&g[(size_t)b * NN + dst], w * s[(size_t)b * NN + src]);
}

// ---------------- partial sums for global mean/var ----------------
__global__ __launch_bounds__(256) void stats_partial(
    const float* __restrict__ g, float* __restrict__ st) {
  int i = blockIdx.x * 256 + threadIdx.x;
  float v = g[i];
  float sum = v, sq = v * v;
#pragma unroll
  for (int off = 32; off; off >>= 1) {
    sum += __shfl_down(sum, off, 64);
    sq += __shfl_down(sq, off, 64);
  }
  __shared__ float s1[4], s2[4];
  int w = threadIdx.x >> 6;
  if ((threadIdx.x & 63) == 0) { s1[w] = sum; s2[w] = sq; }
  __syncthreads();
  if (threadIdx.x == 0) {
    atomicAdd(&st[0], s1[0] + s1[1] + s1[2] + s1[3]);
    atomicAdd(&st[1], s2[0] + s2[1] + s2[2] + s2[3]);
  }
}

// ---------------- final (fp32 out) ----------------
__global__ __launch_bounds__(256) void final_kernel(
    const float* __restrict__ g, const float* __restrict__ st,
    const float* __restrict__ bng, const float* __restrict__ bnb,
    const float* __restrict__ lw, const float* __restrict__ lb,
    float* __restrict__ out) {
  int idx = blockIdx.x * 256 + threadIdx.x;
  if (idx >= NTOT * D_) return;
  int d = idx & (D_ - 1);
  int r = idx >> 7;
  int t = r & (T_ - 1);
  int bn = r >> 7;
  int n = bn & (NA - 1);
  int b = bn >> 6;
  const float invn = 1.f / (float)(B_ * NN);
  float m = st[0] * invn;
  float var = st[1] * invn - m * m;
  float rs = rsqrtf(var + EPS_);
  float gv = g[(size_t)b * NN + t * NA + n];
  float val = (gv - m) * rs * bng[0] + bnb[0];
  out[idx] = val * lw[d] + lb[d];
}

extern "C" void kernel_launch(void* const* d_in, const int* in_sizes, int n_in,
                              void* d_out, int out_size, void* d_ws, size_t ws_size,
                              hipStream_t stream) {
  const float* hist = (const float*)d_in[0];
  const int* eidx = (const int*)d_in[1];
  const float* ew = (const float*)d_in[2];
  const float* hw = (const float*)d_in[3];
  const float* hb = (const float*)d_in[4];
  const float* wq = (const float*)d_in[5];
  const float* bq = (const float*)d_in[6];
  const float* wk = (const float*)d_in[7];
  const float* bk = (const float*)d_in[8];
  const float* wv = (const float*)d_in[9];
  const float* bv = (const float*)d_in[10];
  const float* wo = (const float*)d_in[11];
  const float* bo = (const float*)d_in[12];
  const float* ln1g = (const float*)d_in[13];
  const float* ln1b = (const float*)d_in[14];
  const float* w1 = (const float*)d_in[15];
  const float* b1 = (const float*)d_in[16];
  const float* w2 = (const float*)d_in[17];
  const float* b2 = (const float*)d_in[18];
  const float* ln2g = (const float*)d_in[19];
  const float* ln2b = (const float*)d_in[20];
  const float* bng = (const float*)d_in[21];
  const float* bnb = (const float*)d_in[22];
  const float* lgw = (const float*)d_in[23];
  const float* lgb = (const float*)d_in[24];
  float* out = (float*)d_out;

  float* ws = (float*)d_ws;
  const size_t NE = NE_;
  float* bx = ws + 0 * NE;
  float* be = ws + 1 * NE;
  float* h1 = ws + 2 * NE;
  float* qkv = ws + 3 * NE;   // 3NE, [row][384]
  float* ffmid = ws + 3 * NE; // 4NE, overlaps dead qkv
  float* bs_ = ws + 7 * NE;
  float* bg_ = bs_ + NTOT;
  float* bst = bg_ + NTOT;
  float* pbias = bst + 2;
  const int LW = 196608;
  __bf16* whiB = (__bf16*)(pbias + L_ * QLD);
  __bf16* wloB = whiB + (size_t)L_ * LW;

  convert_weights<<<(L_ * LW + 255) / 256, 256, 0, stream>>>(
      wq, wk, wv, wo, w1, w2, whiB, wloB);
  bias_pack<<<(L_ * QLD + 255) / 256, 256, 0, stream>>>(bq, bk, bv, pbias);
  embed_kernel<<<(NTOT * D_) / 256, 256, 0, stream>>>(hist, hw, hb, bx, be);

  for (int l = 0; l < L_; ++l) {
    const __bf16* hiL = whiB + (size_t)l * LW;
    const __bf16* loL = wloB + (size_t)l * LW;
    // QKV: N=384, K=128, staged A
    gemm_s<0, 128><<<dim3(3, NTOT / 64), 256, 0, stream>>>(
        be, 128, hiL, loL, pbias + l * QLD, nullptr, nullptr, nullptr, qkv, QLD);
    attn_mfma<<<B_ * NA * H_, 256, 0, stream>>>(qkv);
    // O-proj + resid + LN1 -> h1
    gemm_s<2, 128><<<dim3(1, NTOT / 64), 256, 0, stream>>>(
        qkv + 256, QLD, hiL + 49152, loL + 49152, bo + l * D_, be,
        ln1g + l * D_, ln1b + l * D_, h1, 128);
    // FF1 (relu) -> ffmid
    gemm_s<1, 128><<<dim3(4, NTOT / 64), 256, 0, stream>>>(
        h1, 128, hiL + 65536, loL + 65536, b1 + l * DFF, nullptr, nullptr, nullptr,
        ffmid, 512);
    // FF2 + resid + LN2 -> be
    gemm_s<2, 512><<<dim3(1, NTOT / 64), 256, 0, stream>>>(
        ffmid, 512, hiL + 131072, loL + 131072, b2 + l * D_, h1,
        ln2g + l * D_, ln2b + l * D_, be, 128);
  }

  sdot_kernel<<<NTOT / 4, 256, 0, stream>>>(be, bx, bs_);
  hipMemsetAsync(bg_, 0, ((size_t)B_ * NN + 2) * sizeof(float), stream);
  scatter_kernel<<<(B_ * E_) / 256, 256, 0, stream>>>(bs_, eidx, ew, bg_);
  stats_partial<<<(B_ * NN) / 256, 256, 0, stream>>>(bg_, bst);
  final_kernel<<<(NTOT * D_) / 256, 256, 0, stream>>>(bg_, bst, bng, bnb, lgw, lgb, out);
}

// Round 14
// 566.074 us; speedup vs baseline: 1.0645x; 1.0645x over previous
//
#include <hip/hip_runtime.h>
#include <hip/hip_bf16.h>
#include <math.h>

#define EPS_ 1e-5f
constexpr int B_ = 4, NA = 64, T_ = 128, D_ = 128, H_ = 8, L_ = 3, DFF = 512, E_ = 65536;
constexpr int DH = D_ / H_;        // 16
constexpr int NN = T_ * NA;        // 8192
constexpr int NTOT = B_ * NA * T_; // 32768
constexpr int QLD = 384;           // packed QKV row stride
constexpr size_t NE_ = (size_t)NTOT * D_;

typedef __bf16 bf16x8 __attribute__((ext_vector_type(8)));
typedef float f32x4 __attribute__((ext_vector_type(4)));

// ---------------- embed: x = hist@W + b ; e = x + posenc ----------------
__global__ __launch_bounds__(256) void embed_kernel(
    const float* __restrict__ hist, const float* __restrict__ w,
    const float* __restrict__ b, float* __restrict__ x, float* __restrict__ e) {
  int idx = blockIdx.x * 256 + threadIdx.x;
  if (idx >= NTOT * D_) return;
  int d = idx & (D_ - 1);
  int r = idx >> 7;
  int t = r & (T_ - 1);
  const float* hp = hist + (size_t)r * 3;
  float acc = b[d];
  acc += hp[0] * w[0 * D_ + d];
  acc += hp[1] * w[1 * D_ + d];
  acc += hp[2] * w[2 * D_ + d];
  x[idx] = acc;
  int p = d >> 1;
  float ang = (float)t * expf(-logf(10000.f) * (2.f * (float)p) / (float)D_);
  float pe = (d & 1) ? cosf(ang) : sinf(ang);
  e[idx] = acc + pe;
}

// ---------------- weight split into FRAGMENT-LINEAR bf16 hi/lo ----------------
__global__ __launch_bounds__(256) void convert_weights(
    const float* __restrict__ wq, const float* __restrict__ wk,
    const float* __restrict__ wv, const float* __restrict__ wo,
    const float* __restrict__ w1, const float* __restrict__ w2,
    __bf16* __restrict__ hi, __bf16* __restrict__ lo) {
  const int LW = 196608;
  int idx = blockIdx.x * 256 + threadIdx.x;
  if (idx >= L_ * LW) return;
  int l = idx / LW;
  int rem = idx - l * LW;
  float src;
  int n, k, K, segoff;
  if (rem < 49152) { // qkv
    n = rem >> 7; k = rem & 127; K = 128; segoff = 0;
    int which = n >> 7, nl = n & 127;
    const float* W = (which == 0) ? wq : (which == 1) ? wk : wv;
    src = W[(size_t)l * 16384 + k * 128 + nl];
  } else if (rem < 65536) { // wo
    int r2 = rem - 49152;
    n = r2 >> 7; k = r2 & 127; K = 128; segoff = 49152;
    src = wo[(size_t)l * 16384 + k * 128 + n];
  } else if (rem < 131072) { // w1
    int r2 = rem - 65536;
    n = r2 >> 7; k = r2 & 127; K = 128; segoff = 65536;
    src = w1[(size_t)l * 65536 + k * 512 + n];
  } else { // w2
    int r2 = rem - 131072;
    n = r2 >> 9; k = r2 & 511; K = 512; segoff = 131072;
    src = w2[(size_t)l * 65536 + k * 128 + n];
  }
  int nt = n >> 4, kt = k >> 5;
  int lane = ((k >> 3) & 3) * 16 + (n & 15);
  int j = k & 7;
  int dst = l * LW + segoff + ((nt * (K / 32) + kt) * 64 + lane) * 8 + j;
  __bf16 h = (__bf16)src;
  hi[dst] = h;
  lo[dst] = (__bf16)(src - (float)h);
}

// ---------------- pack QKV biases ----------------
__global__ __launch_bounds__(256) void bias_pack(
    const float* __restrict__ bq, const float* __restrict__ bk,
    const float* __restrict__ bv, float* __restrict__ pb) {
  int idx = blockIdx.x * 256 + threadIdx.x;
  if (idx >= L_ * QLD) return;
  int l = idx / QLD, n = idx - l * QLD;
  int which = n >> 7, nl = n & 127;
  const float* src = (which == 0) ? bq : (which == 1) ? bk : bv;
  pb[idx] = src[l * 128 + nl];
}

__device__ __forceinline__ void split8(const float* __restrict__ p,
                                       bf16x8& hi, bf16x8& lo) {
  float4 x0 = *(const float4*)p;
  float4 x1 = *(const float4*)(p + 4);
  float xv[8] = {x0.x, x0.y, x0.z, x0.w, x1.x, x1.y, x1.z, x1.w};
#pragma unroll
  for (int j = 0; j < 8; ++j) {
    __bf16 h = (__bf16)xv[j];
    hi[j] = h;
    lo[j] = (__bf16)(xv[j] - (float)h);
  }
}

// ---------------- MFMA GEMM, 128x128 tile (wave 64x64), frag-linear W ----------------
// Register-resident A (4x reuse both operands) — best for K=128 EPI 0/1 [r12-proven].
template <int EPI, int K>
__global__ __launch_bounds__(256) void gemm_big(
    const float* __restrict__ A, int lda,
    const __bf16* __restrict__ Whi, const __bf16* __restrict__ Wlo,
    const float* __restrict__ bias,
    float* __restrict__ C, int ldc) {
  const int wave = threadIdx.x >> 6;
  const int lane = threadIdx.x & 63;
  const int m16 = lane & 15;
  const int quad = lane >> 4;
  const int wrow = wave >> 1, wcol = wave & 1;
  const int row0 = blockIdx.y * 128 + wrow * 64;
  const int col0 = blockIdx.x * 128 + wcol * 64;
  const int ctb = col0 >> 4;

  f32x4 acc[4][4] = {};
#pragma unroll
  for (int k0 = 0; k0 < K; k0 += 32) {
    bf16x8 ahi[4], alo[4];
#pragma unroll
    for (int mf = 0; mf < 4; ++mf)
      split8(A + (size_t)(row0 + mf * 16 + m16) * lda + k0 + quad * 8, ahi[mf], alo[mf]);
    bf16x8 bhi[4], blo[4];
#pragma unroll
    for (int nf = 0; nf < 4; ++nf) {
      size_t off = ((size_t)(ctb + nf) * (K / 32) + (k0 >> 5)) * 512 + lane * 8;
      bhi[nf] = *(const bf16x8*)(Whi + off);
      blo[nf] = *(const bf16x8*)(Wlo + off);
    }
#pragma unroll
    for (int mf = 0; mf < 4; ++mf)
#pragma unroll
      for (int nf = 0; nf < 4; ++nf) {
        acc[mf][nf] = __builtin_amdgcn_mfma_f32_16x16x32_bf16(ahi[mf], bhi[nf], acc[mf][nf], 0, 0, 0);
        acc[mf][nf] = __builtin_amdgcn_mfma_f32_16x16x32_bf16(ahi[mf], blo[nf], acc[mf][nf], 0, 0, 0);
        acc[mf][nf] = __builtin_amdgcn_mfma_f32_16x16x32_bf16(alo[mf], bhi[nf], acc[mf][nf], 0, 0, 0);
      }
  }
#pragma unroll
  for (int mf = 0; mf < 4; ++mf)
#pragma unroll
    for (int nf = 0; nf < 4; ++nf) {
      int c = col0 + nf * 16 + m16;
      float bj = bias[c];
#pragma unroll
      for (int reg = 0; reg < 4; ++reg) {
        int r = row0 + mf * 16 + quad * 4 + reg;
        float v = acc[mf][nf][reg] + bj;
        if (EPI == 1) v = fmaxf(v, 0.f);
        C[(size_t)r * ldc + c] = v;
      }
    }
}

// ---------------- Staged GEMM + bias + resid + LayerNorm (N==128, grid.x==1) ----------------
// Block 64 rows x 128 cols; A staged per 128-K chunk into LDS (coalesced).
// [r12-proven for K=512; K=128 variant is the round-14 isolation test for O-proj]
template <int K>
__global__ __launch_bounds__(256) void gemm_s_ln(
    const float* __restrict__ A, int lda,
    const __bf16* __restrict__ Whi, const __bf16* __restrict__ Wlo,
    const float* __restrict__ bias, const float* __restrict__ resid,
    const float* __restrict__ lng, const float* __restrict__ lnb,
    float* __restrict__ C) {
  const int wave = threadIdx.x >> 6;
  const int lane = threadIdx.x & 63;
  const int m16 = lane & 15;
  const int quad = lane >> 4;
  const int wrow = wave >> 1, wcol = wave & 1;
  const int grow0 = blockIdx.y * 64;
  const int lrow0 = wrow * 32;
  const int ctb = wcol * 4;

  __shared__ float As[64][129]; // 33 KB; stride 129 -> linear bank spread

  f32x4 acc[2][4] = {};
#pragma unroll
  for (int kc = 0; kc < K / 128; ++kc) {
    if (kc) __syncthreads();
#pragma unroll
    for (int u = 0; u < 8; ++u) {
      int unit = threadIdx.x + u * 256;
      int r = unit >> 5, c4 = unit & 31;
      float4 v = *(const float4*)(A + (size_t)(grow0 + r) * lda + kc * 128 + c4 * 4);
      As[r][c4 * 4 + 0] = v.x;
      As[r][c4 * 4 + 1] = v.y;
      As[r][c4 * 4 + 2] = v.z;
      As[r][c4 * 4 + 3] = v.w;
    }
    __syncthreads();
#pragma unroll
    for (int kt = 0; kt < 4; ++kt) {
      bf16x8 ahi[2], alo[2];
#pragma unroll
      for (int mf = 0; mf < 2; ++mf)
        split8(&As[lrow0 + mf * 16 + m16][kt * 32 + quad * 8], ahi[mf], alo[mf]);
      bf16x8 bhi[4], blo[4];
#pragma unroll
      for (int nf = 0; nf < 4; ++nf) {
        size_t off = ((size_t)(ctb + nf) * (K / 32) + (kc * 4 + kt)) * 512 + lane * 8;
        bhi[nf] = *(const bf16x8*)(Whi + off);
        blo[nf] = *(const bf16x8*)(Wlo + off);
      }
#pragma unroll
      for (int mf = 0; mf < 2; ++mf)
#pragma unroll
        for (int nf = 0; nf < 4; ++nf) {
          acc[mf][nf] = __builtin_amdgcn_mfma_f32_16x16x32_bf16(ahi[mf], bhi[nf], acc[mf][nf], 0, 0, 0);
          acc[mf][nf] = __builtin_amdgcn_mfma_f32_16x16x32_bf16(ahi[mf], blo[nf], acc[mf][nf], 0, 0, 0);
          acc[mf][nf] = __builtin_amdgcn_mfma_f32_16x16x32_bf16(alo[mf], bhi[nf], acc[mf][nf], 0, 0, 0);
        }
    }
  }
  __shared__ float rs[64][2], rq[64][2];
#pragma unroll
  for (int mf = 0; mf < 2; ++mf)
#pragma unroll
    for (int reg = 0; reg < 4; ++reg) {
      int lr = lrow0 + mf * 16 + quad * 4 + reg;
      int gr = grow0 + lr;
      float s = 0.f, qq = 0.f;
#pragma unroll
      for (int nf = 0; nf < 4; ++nf) {
        int c = wcol * 64 + nf * 16 + m16;
        float v = acc[mf][nf][reg] + bias[c] + resid[(size_t)gr * 128 + c];
        acc[mf][nf][reg] = v;
        s += v;
        qq += v * v;
      }
#pragma unroll
      for (int off = 1; off < 16; off <<= 1) {
        s += __shfl_xor(s, off, 64);
        qq += __shfl_xor(qq, off, 64);
      }
      if (m16 == 0) { rs[lr][wcol] = s; rq[lr][wcol] = qq; }
    }
  __syncthreads();
#pragma unroll
  for (int mf = 0; mf < 2; ++mf)
#pragma unroll
    for (int reg = 0; reg < 4; ++reg) {
      int lr = lrow0 + mf * 16 + quad * 4 + reg;
      int gr = grow0 + lr;
      float mean = (rs[lr][0] + rs[lr][1]) * (1.f / 128.f);
      float var = (rq[lr][0] + rq[lr][1]) * (1.f / 128.f) - mean * mean;
      float rstd = rsqrtf(var + EPS_);
#pragma unroll
      for (int nf = 0; nf < 4; ++nf) {
        int c = wcol * 64 + nf * 16 + m16;
        C[(size_t)gr * 128 + c] = (acc[mf][nf][reg] - mean) * rstd * lng[c] + lnb[c];
      }
    }
}

// ---------------- MFMA attention on packed QKV; O overwrites the V slice ----------------
__global__ __launch_bounds__(256) void attn_mfma(float* __restrict__ qkv) {
  const int h = blockIdx.x & (H_ - 1);
  const int bn = blockIdx.x >> 3;
  const int wave = threadIdx.x >> 6;
  const int lane = threadIdx.x & 63;
  const int m16 = lane & 15;
  const int quad = lane >> 4;
  const int row0 = wave * 32;
  const float* Qb = qkv + (size_t)bn * T_ * QLD + h * DH;
  const float* Kb = Qb + 128;
  const float* Vb = Qb + 256;
  float* Ob = (float*)Vb;

  __shared__ __bf16 Plds[4][32][136];

  bf16x8 qhi[2], qlo[2];
#pragma unroll
  for (int mf = 0; mf < 2; ++mf) {
    if (quad < 2) {
      split8(Qb + (size_t)(row0 + mf * 16 + m16) * QLD + quad * 8, qhi[mf], qlo[mf]);
    } else {
#pragma unroll
      for (int j = 0; j < 8; ++j) { qhi[mf][j] = (__bf16)0.f; qlo[mf][j] = (__bf16)0.f; }
    }
  }

  f32x4 acc[2][8] = {};
#pragma unroll
  for (int nf = 0; nf < 8; ++nf) {
    bf16x8 khi, klo;
    if (quad < 2) {
      split8(Kb + (size_t)(nf * 16 + m16) * QLD + quad * 8, khi, klo);
    } else {
#pragma unroll
      for (int j = 0; j < 8; ++j) { khi[j] = (__bf16)0.f; klo[j] = (__bf16)0.f; }
    }
#pragma unroll
    for (int mf = 0; mf < 2; ++mf) {
      acc[mf][nf] = __builtin_amdgcn_mfma_f32_16x16x32_bf16(qhi[mf], khi, acc[mf][nf], 0, 0, 0);
      acc[mf][nf] = __builtin_amdgcn_mfma_f32_16x16x32_bf16(qhi[mf], klo, acc[mf][nf], 0, 0, 0);
      acc[mf][nf] = __builtin_amdgcn_mfma_f32_16x16x32_bf16(qlo[mf], khi, acc[mf][nf], 0, 0, 0);
    }
  }

  const float scale = 0.25f;
#pragma unroll
  for (int mf = 0; mf < 2; ++mf)
#pragma unroll
    for (int reg = 0; reg < 4; ++reg) {
      float mx = -1e30f;
#pragma unroll
      for (int nf = 0; nf < 8; ++nf) mx = fmaxf(mx, acc[mf][nf][reg]);
#pragma unroll
      for (int off = 1; off < 16; off <<= 1) mx = fmaxf(mx, __shfl_xor(mx, off, 64));
      float sum = 0.f;
#pragma unroll
      for (int nf = 0; nf < 8; ++nf) {
        float e = __expf((acc[mf][nf][reg] - mx) * scale);
        acc[mf][nf][reg] = e;
        sum += e;
      }
#pragma unroll
      for (int off = 1; off < 16; off <<= 1) sum += __shfl_xor(sum, off, 64);
      float inv = 1.f / sum;
#pragma unroll
      for (int nf = 0; nf < 8; ++nf) acc[mf][nf][reg] *= inv;
    }

#pragma unroll
  for (int mf = 0; mf < 2; ++mf)
#pragma unroll
    for (int nf = 0; nf < 8; ++nf)
#pragma unroll
      for (int reg = 0; reg < 4; ++reg)
        Plds[wave][mf * 16 + quad * 4 + reg][nf * 16 + m16] = (__bf16)acc[mf][nf][reg];

  f32x4 oacc[2] = {};
#pragma unroll
  for (int kc = 0; kc < 4; ++kc) {
    bf16x8 pa0 = *(const bf16x8*)&Plds[wave][m16][kc * 32 + quad * 8];
    bf16x8 pa1 = *(const bf16x8*)&Plds[wave][16 + m16][kc * 32 + quad * 8];
    bf16x8 vhi, vlo;
#pragma unroll
    for (int j = 0; j < 8; ++j) {
      float x = Vb[(size_t)(kc * 32 + quad * 8 + j) * QLD + m16];
      __bf16 hh = (__bf16)x;
      vhi[j] = hh;
      vlo[j] = (__bf16)(x - (float)hh);
    }
    oacc[0] = __builtin_amdgcn_mfma_f32_16x16x32_bf16(pa0, vhi, oacc[0], 0, 0, 0);
    oacc[0] = __builtin_amdgcn_mfma_f32_16x16x32_bf16(pa0, vlo, oacc[0], 0, 0, 0);
    oacc[1] = __builtin_amdgcn_mfma_f32_16x16x32_bf16(pa1, vhi, oacc[1], 0, 0, 0);
    oacc[1] = __builtin_amdgcn_mfma_f32_16x16x32_bf16(pa1, vlo, oacc[1], 0, 0, 0);
  }

  __syncthreads();
#pragma unroll
  for (int mf = 0; mf < 2; ++mf)
#pragma unroll
    for (int reg = 0; reg < 4; ++reg) {
      int r = row0 + mf * 16 + quad * 4 + reg;
      Ob[(size_t)r * QLD + m16] = oacc[mf][reg];
    }
}

// ---------------- gating dot ----------------
__global__ __launch_bounds__(256) void sdot_kernel(
    const float* __restrict__ e, const float* __restrict__ x, float* __restrict__ s) {
  int r = blockIdx.x * 4 + (threadIdx.x >> 6);
  int lane = threadIdx.x & 63;
  const float* ep = e + (size_t)r * D_;
  const float* xp = x + (size_t)r * D_;
  float acc = ep[lane] * xp[lane] + ep[lane + 64] * xp[lane + 64];
#pragma unroll
  for (int off = 32; off; off >>= 1) acc += __shfl_down(acc, off, 64);
  if (lane == 0) {
    int t = r & (T_ - 1);
    int bn = r >> 7;
    int n = bn & (NA - 1);
    int b = bn >> 6;
    s[(size_t)b * NN + t * NA + n] = acc;
  }
}

// ---------------- edge scatter ----------------
__global__ __launch_bounds__(256) void scatter_kernel(
    const float* __restrict__ s, const int* __restrict__ ei,
    const float* __restrict__ ew, float* __restrict__ g) {
  int idx = blockIdx.x * 256 + threadIdx.x;
  if (idx >= B_ * E_) return;
  int b = idx >> 16;
  int e = idx & (E_ - 1);
  int src = ei[(size_t)b * 2 * E_ + e];
  int dst = ei[(size_t)b * 2 * E_ + E_ + e];
  float w = ew[(size_t)b * E_ + e];
  atomicAdd(&g[(size_t)b * NN + dst], w * s[(size_t)b * NN + src]);
}

// ---------------- partial sums for global mean/var ----------------
__global__ __launch_bounds__(256) void stats_partial(
    const float* __restrict__ g, float* __restrict__ st) {
  int i = blockIdx.x * 256 + threadIdx.x;
  float v = g[i];
  float sum = v, sq = v * v;
#pragma unroll
  for (int off = 32; off; off >>= 1) {
    sum += __shfl_down(sum, off, 64);
    sq += __shfl_down(sq, off, 64);
  }
  __shared__ float s1[4], s2[4];
  int w = threadIdx.x >> 6;
  if ((threadIdx.x & 63) == 0) { s1[w] = sum; s2[w] = sq; }
  __syncthreads();
  if (threadIdx.x == 0) {
    atomicAdd(&st[0], s1[0] + s1[1] + s1[2] + s1[3]);
    atomicAdd(&st[1], s2[0] + s2[1] + s2[2] + s2[3]);
  }
}

// ---------------- final (fp32 out) ----------------
__global__ __launch_bounds__(256) void final_kernel(
    const float* __restrict__ g, const float* __restrict__ st,
    const float* __restrict__ bng, const float* __restrict__ bnb,
    const float* __restrict__ lw, const float* __restrict__ lb,
    float* __restrict__ out) {
  int idx = blockIdx.x * 256 + threadIdx.x;
  if (idx >= NTOT * D_) return;
  int d = idx & (D_ - 1);
  int r = idx >> 7;
  int t = r & (T_ - 1);
  int bn = r >> 7;
  int n = bn & (NA - 1);
  int b = bn >> 6;
  const float invn = 1.f / (float)(B_ * NN);
  float m = st[0] * invn;
  float var = st[1] * invn - m * m;
  float rs = rsqrtf(var + EPS_);
  float gv = g[(size_t)b * NN + t * NA + n];
  float val = (gv - m) * rs * bng[0] + bnb[0];
  out[idx] = val * lw[d] + lb[d];
}

extern "C" void kernel_launch(void* const* d_in, const int* in_sizes, int n_in,
                              void* d_out, int out_size, void* d_ws, size_t ws_size,
                              hipStream_t stream) {
  const float* hist = (const float*)d_in[0];
  const int* eidx = (const int*)d_in[1];
  const float* ew = (const float*)d_in[2];
  const float* hw = (const float*)d_in[3];
  const float* hb = (const float*)d_in[4];
  const float* wq = (const float*)d_in[5];
  const float* bq = (const float*)d_in[6];
  const float* wk = (const float*)d_in[7];
  const float* bk = (const float*)d_in[8];
  const float* wv = (const float*)d_in[9];
  const float* bv = (const float*)d_in[10];
  const float* wo = (const float*)d_in[11];
  const float* bo = (const float*)d_in[12];
  const float* ln1g = (const float*)d_in[13];
  const float* ln1b = (const float*)d_in[14];
  const float* w1 = (const float*)d_in[15];
  const float* b1 = (const float*)d_in[16];
  const float* w2 = (const float*)d_in[17];
  const float* b2 = (const float*)d_in[18];
  const float* ln2g = (const float*)d_in[19];
  const float* ln2b = (const float*)d_in[20];
  const float* bng = (const float*)d_in[21];
  const float* bnb = (const float*)d_in[22];
  const float* lgw = (const float*)d_in[23];
  const float* lgb = (const float*)d_in[24];
  float* out = (float*)d_out;

  float* ws = (float*)d_ws;
  const size_t NE = NE_;
  float* bx = ws + 0 * NE;
  float* be = ws + 1 * NE;
  float* h1 = ws + 2 * NE;
  float* qkv = ws + 3 * NE;   // 3NE, [row][384]
  float* ffmid = ws + 3 * NE; // 4NE, overlaps dead qkv
  float* bs_ = ws + 7 * NE;
  float* bg_ = bs_ + NTOT;
  float* bst = bg_ + NTOT;
  float* pbias = bst + 2;
  const int LW = 196608;
  __bf16* whiB = (__bf16*)(pbias + L_ * QLD);
  __bf16* wloB = whiB + (size_t)L_ * LW;

  convert_weights<<<(L_ * LW + 255) / 256, 256, 0, stream>>>(
      wq, wk, wv, wo, w1, w2, whiB, wloB);
  bias_pack<<<(L_ * QLD + 255) / 256, 256, 0, stream>>>(bq, bk, bv, pbias);
  embed_kernel<<<(NTOT * D_) / 256, 256, 0, stream>>>(hist, hw, hb, bx, be);

  for (int l = 0; l < L_; ++l) {
    const __bf16* hiL = whiB + (size_t)l * LW;
    const __bf16* loL = wloB + (size_t)l * LW;
    // QKV: register-resident gemm_big (r12-proven)
    gemm_big<0, 128><<<dim3(3, NTOT / 128), 256, 0, stream>>>(
        be, 128, hiL, loL, pbias + l * QLD, qkv, QLD);
    attn_mfma<<<B_ * NA * H_, 256, 0, stream>>>(qkv);
    // O-proj + resid + LN1 -> h1 (staged A — round-14 isolation test)
    gemm_s_ln<128><<<dim3(1, NTOT / 64), 256, 0, stream>>>(
        qkv + 256, QLD, hiL + 49152, loL + 49152, bo + l * D_, be,
        ln1g + l * D_, ln1b + l * D_, h1);
    // FF1 (relu): register-resident gemm_big (r12-proven)
    gemm_big<1, 128><<<dim3(4, NTOT / 128), 256, 0, stream>>>(
        h1, 128, hiL + 65536, loL + 65536, b1 + l * DFF, ffmid, 512);
    // FF2 + resid + LN2 -> be (staged, r12-proven)
    gemm_s_ln<512><<<dim3(1, NTOT / 64), 256, 0, stream>>>(
        ffmid, 512, hiL + 131072, loL + 131072, b2 + l * D_, h1,
        ln2g + l * D_, ln2b + l * D_, be);
  }

  sdot_kernel<<<NTOT / 4, 256, 0, stream>>>(be, bx, bs_);
  hipMemsetAsync(bg_, 0, ((size_t)B_ * NN + 2) * sizeof(float), stream);
  scatter_kernel<<<(B_ * E_) / 256, 256, 0, stream>>>(bs_, eidx, ew, bg_);
  stats_partial<<<(B_ * NN) / 256, 256, 0, stream>>>(bg_, bst);
  final_kernel<<<(NTOT * D_) / 256, 256, 0, stream>>>(bg_, bst, bng, bnb, lgw, lgb, out);
}

// Round 15
// 554.449 us; speedup vs baseline: 1.0868x; 1.0210x over previous
//
#include <hip/hip_runtime.h>
#include <hip/hip_bf16.h>
#include <math.h>

#define EPS_ 1e-5f
constexpr int B_ = 4, NA = 64, T_ = 128, D_ = 128, H_ = 8, L_ = 3, DFF = 512, E_ = 65536;
constexpr int DH = D_ / H_;        // 16
constexpr int NN = T_ * NA;        // 8192
constexpr int NTOT = B_ * NA * T_; // 32768
constexpr int QLD = 384;           // packed QKV row stride
constexpr size_t NE_ = (size_t)NTOT * D_;

typedef __bf16 bf16x8 __attribute__((ext_vector_type(8)));
typedef float f32x4 __attribute__((ext_vector_type(4)));

// ---------------- embed: x = hist@W + b ; e = x + posenc ----------------
__global__ __launch_bounds__(256) void embed_kernel(
    const float* __restrict__ hist, const float* __restrict__ w,
    const float* __restrict__ b, float* __restrict__ x, float* __restrict__ e) {
  int idx = blockIdx.x * 256 + threadIdx.x;
  if (idx >= NTOT * D_) return;
  int d = idx & (D_ - 1);
  int r = idx >> 7;
  int t = r & (T_ - 1);
  const float* hp = hist + (size_t)r * 3;
  float acc = b[d];
  acc += hp[0] * w[0 * D_ + d];
  acc += hp[1] * w[1 * D_ + d];
  acc += hp[2] * w[2 * D_ + d];
  x[idx] = acc;
  int p = d >> 1;
  float ang = (float)t * expf(-logf(10000.f) * (2.f * (float)p) / (float)D_);
  float pe = (d & 1) ? cosf(ang) : sinf(ang);
  e[idx] = acc + pe;
}

// ---------------- weight split into FRAGMENT-LINEAR bf16 hi/lo ----------------
__global__ __launch_bounds__(256) void convert_weights(
    const float* __restrict__ wq, const float* __restrict__ wk,
    const float* __restrict__ wv, const float* __restrict__ wo,
    const float* __restrict__ w1, const float* __restrict__ w2,
    __bf16* __restrict__ hi, __bf16* __restrict__ lo) {
  const int LW = 196608;
  int idx = blockIdx.x * 256 + threadIdx.x;
  if (idx >= L_ * LW) return;
  int l = idx / LW;
  int rem = idx - l * LW;
  float src;
  int n, k, K, segoff;
  if (rem < 49152) { // qkv
    n = rem >> 7; k = rem & 127; K = 128; segoff = 0;
    int which = n >> 7, nl = n & 127;
    const float* W = (which == 0) ? wq : (which == 1) ? wk : wv;
    src = W[(size_t)l * 16384 + k * 128 + nl];
  } else if (rem < 65536) { // wo
    int r2 = rem - 49152;
    n = r2 >> 7; k = r2 & 127; K = 128; segoff = 49152;
    src = wo[(size_t)l * 16384 + k * 128 + n];
  } else if (rem < 131072) { // w1
    int r2 = rem - 65536;
    n = r2 >> 7; k = r2 & 127; K = 128; segoff = 65536;
    src = w1[(size_t)l * 65536 + k * 512 + n];
  } else { // w2
    int r2 = rem - 131072;
    n = r2 >> 9; k = r2 & 511; K = 512; segoff = 131072;
    src = w2[(size_t)l * 65536 + k * 128 + n];
  }
  int nt = n >> 4, kt = k >> 5;
  int lane = ((k >> 3) & 3) * 16 + (n & 15);
  int j = k & 7;
  int dst = l * LW + segoff + ((nt * (K / 32) + kt) * 64 + lane) * 8 + j;
  __bf16 h = (__bf16)src;
  hi[dst] = h;
  lo[dst] = (__bf16)(src - (float)h);
}

// ---------------- pack QKV biases ----------------
__global__ __launch_bounds__(256) void bias_pack(
    const float* __restrict__ bq, const float* __restrict__ bk,
    const float* __restrict__ bv, float* __restrict__ pb) {
  int idx = blockIdx.x * 256 + threadIdx.x;
  if (idx >= L_ * QLD) return;
  int l = idx / QLD, n = idx - l * QLD;
  int which = n >> 7, nl = n & 127;
  const float* src = (which == 0) ? bq : (which == 1) ? bk : bv;
  pb[idx] = src[l * 128 + nl];
}

__device__ __forceinline__ void split8(const float* __restrict__ p,
                                       bf16x8& hi, bf16x8& lo) {
  float4 x0 = *(const float4*)p;
  float4 x1 = *(const float4*)(p + 4);
  float xv[8] = {x0.x, x0.y, x0.z, x0.w, x1.x, x1.y, x1.z, x1.w};
#pragma unroll
  for (int j = 0; j < 8; ++j) {
    __bf16 h = (__bf16)xv[j];
    hi[j] = h;
    lo[j] = (__bf16)(xv[j] - (float)h);
  }
}

// ---------------- MFMA GEMM, 128x128 tile (wave 64x64), frag-linear W [r12] ----------------
template <int EPI, int K>
__global__ __launch_bounds__(256) void gemm_big(
    const float* __restrict__ A, int lda,
    const __bf16* __restrict__ Whi, const __bf16* __restrict__ Wlo,
    const float* __restrict__ bias,
    float* __restrict__ C, int ldc) {
  const int wave = threadIdx.x >> 6;
  const int lane = threadIdx.x & 63;
  const int m16 = lane & 15;
  const int quad = lane >> 4;
  const int wrow = wave >> 1, wcol = wave & 1;
  const int row0 = blockIdx.y * 128 + wrow * 64;
  const int col0 = blockIdx.x * 128 + wcol * 64;
  const int ctb = col0 >> 4;

  f32x4 acc[4][4] = {};
#pragma unroll
  for (int k0 = 0; k0 < K; k0 += 32) {
    bf16x8 ahi[4], alo[4];
#pragma unroll
    for (int mf = 0; mf < 4; ++mf)
      split8(A + (size_t)(row0 + mf * 16 + m16) * lda + k0 + quad * 8, ahi[mf], alo[mf]);
    bf16x8 bhi[4], blo[4];
#pragma unroll
    for (int nf = 0; nf < 4; ++nf) {
      size_t off = ((size_t)(ctb + nf) * (K / 32) + (k0 >> 5)) * 512 + lane * 8;
      bhi[nf] = *(const bf16x8*)(Whi + off);
      blo[nf] = *(const bf16x8*)(Wlo + off);
    }
#pragma unroll
    for (int mf = 0; mf < 4; ++mf)
#pragma unroll
      for (int nf = 0; nf < 4; ++nf) {
        acc[mf][nf] = __builtin_amdgcn_mfma_f32_16x16x32_bf16(ahi[mf], bhi[nf], acc[mf][nf], 0, 0, 0);
        acc[mf][nf] = __builtin_amdgcn_mfma_f32_16x16x32_bf16(ahi[mf], blo[nf], acc[mf][nf], 0, 0, 0);
        acc[mf][nf] = __builtin_amdgcn_mfma_f32_16x16x32_bf16(alo[mf], bhi[nf], acc[mf][nf], 0, 0, 0);
      }
  }
#pragma unroll
  for (int mf = 0; mf < 4; ++mf)
#pragma unroll
    for (int nf = 0; nf < 4; ++nf) {
      int c = col0 + nf * 16 + m16;
      float bj = bias[c];
#pragma unroll
      for (int reg = 0; reg < 4; ++reg) {
        int r = row0 + mf * 16 + quad * 4 + reg;
        float v = acc[mf][nf][reg] + bj;
        if (EPI == 1) v = fmaxf(v, 0.f);
        C[(size_t)r * ldc + c] = v;
      }
    }
}

// ---------------- GEMM + bias + resid + LayerNorm; block 64x128, register A [r12] ----------------
template <int K>
__global__ __launch_bounds__(256) void gemm_ln(
    const float* __restrict__ A, int lda,
    const __bf16* __restrict__ Whi, const __bf16* __restrict__ Wlo,
    const float* __restrict__ bias, const float* __restrict__ resid,
    const float* __restrict__ lng, const float* __restrict__ lnb,
    float* __restrict__ C) {
  const int wave = threadIdx.x >> 6;
  const int lane = threadIdx.x & 63;
  const int m16 = lane & 15;
  const int quad = lane >> 4;
  const int wrow = wave >> 1, wcol = wave & 1;
  const int row0 = blockIdx.y * 64 + wrow * 32;
  const int col0 = wcol * 64;
  const int ctb = wcol * 4;

  f32x4 acc[2][4] = {};
#pragma unroll
  for (int k0 = 0; k0 < K; k0 += 32) {
    bf16x8 ahi[2], alo[2];
#pragma unroll
    for (int mf = 0; mf < 2; ++mf)
      split8(A + (size_t)(row0 + mf * 16 + m16) * lda + k0 + quad * 8, ahi[mf], alo[mf]);
    bf16x8 bhi[4], blo[4];
#pragma unroll
    for (int nf = 0; nf < 4; ++nf) {
      size_t off = ((size_t)(ctb + nf) * (K / 32) + (k0 >> 5)) * 512 + lane * 8;
      bhi[nf] = *(const bf16x8*)(Whi + off);
      blo[nf] = *(const bf16x8*)(Wlo + off);
    }
#pragma unroll
    for (int mf = 0; mf < 2; ++mf)
#pragma unroll
      for (int nf = 0; nf < 4; ++nf) {
        acc[mf][nf] = __builtin_amdgcn_mfma_f32_16x16x32_bf16(ahi[mf], bhi[nf], acc[mf][nf], 0, 0, 0);
        acc[mf][nf] = __builtin_amdgcn_mfma_f32_16x16x32_bf16(ahi[mf], blo[nf], acc[mf][nf], 0, 0, 0);
        acc[mf][nf] = __builtin_amdgcn_mfma_f32_16x16x32_bf16(alo[mf], bhi[nf], acc[mf][nf], 0, 0, 0);
      }
  }
  __shared__ float rs[64][2], rq[64][2];
#pragma unroll
  for (int mf = 0; mf < 2; ++mf)
#pragma unroll
    for (int reg = 0; reg < 4; ++reg) {
      int lr = wrow * 32 + mf * 16 + quad * 4 + reg;
      int gr = blockIdx.y * 64 + lr;
      float s = 0.f, qq = 0.f;
#pragma unroll
      for (int nf = 0; nf < 4; ++nf) {
        int c = col0 + nf * 16 + m16;
        float v = acc[mf][nf][reg] + bias[c] + resid[(size_t)gr * 128 + c];
        acc[mf][nf][reg] = v;
        s += v;
        qq += v * v;
      }
#pragma unroll
      for (int off = 1; off < 16; off <<= 1) {
        s += __shfl_xor(s, off, 64);
        qq += __shfl_xor(qq, off, 64);
      }
      if (m16 == 0) { rs[lr][wcol] = s; rq[lr][wcol] = qq; }
    }
  __syncthreads();
#pragma unroll
  for (int mf = 0; mf < 2; ++mf)
#pragma unroll
    for (int reg = 0; reg < 4; ++reg) {
      int lr = wrow * 32 + mf * 16 + quad * 4 + reg;
      int gr = blockIdx.y * 64 + lr;
      float mean = (rs[lr][0] + rs[lr][1]) * (1.f / 128.f);
      float var = (rq[lr][0] + rq[lr][1]) * (1.f / 128.f) - mean * mean;
      float rstd = rsqrtf(var + EPS_);
#pragma unroll
      for (int nf = 0; nf < 4; ++nf) {
        int c = col0 + nf * 16 + m16;
        C[(size_t)gr * 128 + c] = (acc[mf][nf][reg] - mean) * rstd * lng[c] + lnb[c];
      }
    }
}

// ---------------- FF2 + LN (staged A, K=512) [r12]; SDOT fuses gating dot ----------------
template <int SDOT>
__global__ __launch_bounds__(256) void ff2_ln(
    const float* __restrict__ A, // ffmid [M][512]
    const __bf16* __restrict__ Whi, const __bf16* __restrict__ Wlo,
    const float* __restrict__ bias, const float* __restrict__ resid,
    const float* __restrict__ lng, const float* __restrict__ lnb,
    float* __restrict__ C,
    const float* __restrict__ bx, float* __restrict__ sdst) {
  const int wave = threadIdx.x >> 6;
  const int lane = threadIdx.x & 63;
  const int m16 = lane & 15;
  const int quad = lane >> 4;
  const int wrow = wave >> 1, wcol = wave & 1;
  const int grow0 = blockIdx.y * 64;
  const int lrow0 = wrow * 32;
  const int col0 = wcol * 64;
  const int ctb = wcol * 4;

  __shared__ float As[64][129];

  f32x4 acc[2][4] = {};
  for (int kc = 0; kc < 4; ++kc) {
    if (kc) __syncthreads();
#pragma unroll
    for (int u = 0; u < 8; ++u) {
      int unit = threadIdx.x + u * 256;
      int r = unit >> 5, c4 = unit & 31;
      float4 v = *(const float4*)(A + (size_t)(grow0 + r) * 512 + kc * 128 + c4 * 4);
      As[r][c4 * 4 + 0] = v.x;
      As[r][c4 * 4 + 1] = v.y;
      As[r][c4 * 4 + 2] = v.z;
      As[r][c4 * 4 + 3] = v.w;
    }
    __syncthreads();
#pragma unroll
    for (int kt = 0; kt < 4; ++kt) {
      bf16x8 ahi[2], alo[2];
#pragma unroll
      for (int mf = 0; mf < 2; ++mf)
        split8(&As[lrow0 + mf * 16 + m16][kt * 32 + quad * 8], ahi[mf], alo[mf]);
      bf16x8 bhi[4], blo[4];
#pragma unroll
      for (int nf = 0; nf < 4; ++nf) {
        size_t off = ((size_t)(ctb + nf) * 16 + (kc * 4 + kt)) * 512 + lane * 8;
        bhi[nf] = *(const bf16x8*)(Whi + off);
        blo[nf] = *(const bf16x8*)(Wlo + off);
      }
#pragma unroll
      for (int mf = 0; mf < 2; ++mf)
#pragma unroll
        for (int nf = 0; nf < 4; ++nf) {
          acc[mf][nf] = __builtin_amdgcn_mfma_f32_16x16x32_bf16(ahi[mf], bhi[nf], acc[mf][nf], 0, 0, 0);
          acc[mf][nf] = __builtin_amdgcn_mfma_f32_16x16x32_bf16(ahi[mf], blo[nf], acc[mf][nf], 0, 0, 0);
          acc[mf][nf] = __builtin_amdgcn_mfma_f32_16x16x32_bf16(alo[mf], bhi[nf], acc[mf][nf], 0, 0, 0);
        }
    }
  }
  __shared__ float rs[64][2], rq[64][2];
  __shared__ float sd[64][2];
#pragma unroll
  for (int mf = 0; mf < 2; ++mf)
#pragma unroll
    for (int reg = 0; reg < 4; ++reg) {
      int lr = lrow0 + mf * 16 + quad * 4 + reg;
      int gr = grow0 + lr;
      float s = 0.f, qq = 0.f;
#pragma unroll
      for (int nf = 0; nf < 4; ++nf) {
        int c = col0 + nf * 16 + m16;
        float v = acc[mf][nf][reg] + bias[c] + resid[(size_t)gr * 128 + c];
        acc[mf][nf][reg] = v;
        s += v;
        qq += v * v;
      }
#pragma unroll
      for (int off = 1; off < 16; off <<= 1) {
        s += __shfl_xor(s, off, 64);
        qq += __shfl_xor(qq, off, 64);
      }
      if (m16 == 0) { rs[lr][wcol] = s; rq[lr][wcol] = qq; }
    }
  __syncthreads();
#pragma unroll
  for (int mf = 0; mf < 2; ++mf)
#pragma unroll
    for (int reg = 0; reg < 4; ++reg) {
      int lr = lrow0 + mf * 16 + quad * 4 + reg;
      int gr = grow0 + lr;
      float mean = (rs[lr][0] + rs[lr][1]) * (1.f / 128.f);
      float var = (rq[lr][0] + rq[lr][1]) * (1.f / 128.f) - mean * mean;
      float rstd = rsqrtf(var + EPS_);
      float sdp = 0.f;
#pragma unroll
      for (int nf = 0; nf < 4; ++nf) {
        int c = col0 + nf * 16 + m16;
        float v = (acc[mf][nf][reg] - mean) * rstd * lng[c] + lnb[c];
        C[(size_t)gr * 128 + c] = v;
        if (SDOT) sdp += v * bx[(size_t)gr * 128 + c];
      }
      if (SDOT) {
#pragma unroll
        for (int off = 1; off < 16; off <<= 1) sdp += __shfl_xor(sdp, off, 64);
        if (m16 == 0) sd[lr][wcol] = sdp;
      }
    }
  if (SDOT) {
    __syncthreads();
    if (threadIdx.x < 64) {
      int lr = threadIdx.x;
      int gr = grow0 + lr;
      float sv = sd[lr][0] + sd[lr][1];
      int t = gr & (T_ - 1);
      int bn = gr >> 7;
      int n = bn & (NA - 1);
      int b = bn >> 6;
      sdst[(size_t)b * NN + t * NA + n] = sv;
    }
  }
}

// ---------------- MFMA attention on packed QKV; O overwrites the V slice ----------------
__global__ __launch_bounds__(256) void attn_mfma(float* __restrict__ qkv) {
  const int h = blockIdx.x & (H_ - 1);
  const int bn = blockIdx.x >> 3;
  const int wave = threadIdx.x >> 6;
  const int lane = threadIdx.x & 63;
  const int m16 = lane & 15;
  const int quad = lane >> 4;
  const int row0 = wave * 32;
  const float* Qb = qkv + (size_t)bn * T_ * QLD + h * DH;
  const float* Kb = Qb + 128;
  const float* Vb = Qb + 256;
  float* Ob = (float*)Vb;

  __shared__ __bf16 Plds[4][32][136];

  bf16x8 qhi[2], qlo[2];
#pragma unroll
  for (int mf = 0; mf < 2; ++mf) {
    if (quad < 2) {
      split8(Qb + (size_t)(row0 + mf * 16 + m16) * QLD + quad * 8, qhi[mf], qlo[mf]);
    } else {
#pragma unroll
      for (int j = 0; j < 8; ++j) { qhi[mf][j] = (__bf16)0.f; qlo[mf][j] = (__bf16)0.f; }
    }
  }

  f32x4 acc[2][8] = {};
#pragma unroll
  for (int nf = 0; nf < 8; ++nf) {
    bf16x8 khi, klo;
    if (quad < 2) {
      split8(Kb + (size_t)(nf * 16 + m16) * QLD + quad * 8, khi, klo);
    } else {
#pragma unroll
      for (int j = 0; j < 8; ++j) { khi[j] = (__bf16)0.f; klo[j] = (__bf16)0.f; }
    }
#pragma unroll
    for (int mf = 0; mf < 2; ++mf) {
      acc[mf][nf] = __builtin_amdgcn_mfma_f32_16x16x32_bf16(qhi[mf], khi, acc[mf][nf], 0, 0, 0);
      acc[mf][nf] = __builtin_amdgcn_mfma_f32_16x16x32_bf16(qhi[mf], klo, acc[mf][nf], 0, 0, 0);
      acc[mf][nf] = __builtin_amdgcn_mfma_f32_16x16x32_bf16(qlo[mf], khi, acc[mf][nf], 0, 0, 0);
    }
  }

  const float scale = 0.25f;
#pragma unroll
  for (int mf = 0; mf < 2; ++mf)
#pragma unroll
    for (int reg = 0; reg < 4; ++reg) {
      float mx = -1e30f;
#pragma unroll
      for (int nf = 0; nf < 8; ++nf) mx = fmaxf(mx, acc[mf][nf][reg]);
#pragma unroll
      for (int off = 1; off < 16; off <<= 1) mx = fmaxf(mx, __shfl_xor(mx, off, 64));
      float sum = 0.f;
#pragma unroll
      for (int nf = 0; nf < 8; ++nf) {
        float e = __expf((acc[mf][nf][reg] - mx) * scale);
        acc[mf][nf][reg] = e;
        sum += e;
      }
#pragma unroll
      for (int off = 1; off < 16; off <<= 1) sum += __shfl_xor(sum, off, 64);
      float inv = 1.f / sum;
#pragma unroll
      for (int nf = 0; nf < 8; ++nf) acc[mf][nf][reg] *= inv;
    }

#pragma unroll
  for (int mf = 0; mf < 2; ++mf)
#pragma unroll
    for (int nf = 0; nf < 8; ++nf)
#pragma unroll
      for (int reg = 0; reg < 4; ++reg)
        Plds[wave][mf * 16 + quad * 4 + reg][nf * 16 + m16] = (__bf16)acc[mf][nf][reg];

  f32x4 oacc[2] = {};
#pragma unroll
  for (int kc = 0; kc < 4; ++kc) {
    bf16x8 pa0 = *(const bf16x8*)&Plds[wave][m16][kc * 32 + quad * 8];
    bf16x8 pa1 = *(const bf16x8*)&Plds[wave][16 + m16][kc * 32 + quad * 8];
    bf16x8 vhi, vlo;
#pragma unroll
    for (int j = 0; j < 8; ++j) {
      float x = Vb[(size_t)(kc * 32 + quad * 8 + j) * QLD + m16];
      __bf16 hh = (__bf16)x;
      vhi[j] = hh;
      vlo[j] = (__bf16)(x - (float)hh);
    }
    oacc[0] = __builtin_amdgcn_mfma_f32_16x16x32_bf16(pa0, vhi, oacc[0], 0, 0, 0);
    oacc[0] = __builtin_amdgcn_mfma_f32_16x16x32_bf16(pa0, vlo, oacc[0], 0, 0, 0);
    oacc[1] = __builtin_amdgcn_mfma_f32_16x16x32_bf16(pa1, vhi, oacc[1], 0, 0, 0);
    oacc[1] = __builtin_amdgcn_mfma_f32_16x16x32_bf16(pa1, vlo, oacc[1], 0, 0, 0);
  }

  __syncthreads();
#pragma unroll
  for (int mf = 0; mf < 2; ++mf)
#pragma unroll
    for (int reg = 0; reg < 4; ++reg) {
      int r = row0 + mf * 16 + quad * 4 + reg;
      Ob[(size_t)r * QLD + m16] = oacc[mf][reg];
    }
}

// ---------------- edge scatter ----------------
__global__ __launch_bounds__(256) void scatter_kernel(
    const float* __restrict__ s, const int* __restrict__ ei,
    const float* __restrict__ ew, float* __restrict__ g) {
  int idx = blockIdx.x * 256 + threadIdx.x;
  if (idx >= B_ * E_) return;
  int b = idx >> 16;
  int e = idx & (E_ - 1);
  int src = ei[(size_t)b * 2 * E_ + e];
  int dst = ei[(size_t)b * 2 * E_ + E_ + e];
  float w = ew[(size_t)b * E_ + e];
  atomicAdd(&g[(size_t)b * NN + dst], w * s[(size_t)b * NN + src]);
}

// ---------------- partial sums for global mean/var ----------------
__global__ __launch_bounds__(256) void stats_partial(
    const float* __restrict__ g, float* __restrict__ st) {
  int i = blockIdx.x * 256 + threadIdx.x;
  float v = g[i];
  float sum = v, sq = v * v;
#pragma unroll
  for (int off = 32; off; off >>= 1) {
    sum += __shfl_down(sum, off, 64);
    sq += __shfl_down(sq, off, 64);
  }
  __shared__ float s1[4], s2[4];
  int w = threadIdx.x >> 6;
  if ((threadIdx.x & 63) == 0) { s1[w] = sum; s2[w] = sq; }
  __syncthreads();
  if (threadIdx.x == 0) {
    atomicAdd(&st[0], s1[0] + s1[1] + s1[2] + s1[3]);
    atomicAdd(&st[1], s2[0] + s2[1] + s2[2] + s2[3]);
  }
}

// ---------------- final (fp32 out) ----------------
__global__ __launch_bounds__(256) void final_kernel(
    const float* __restrict__ g, const float* __restrict__ st,
    const float* __restrict__ bng, const float* __restrict__ bnb,
    const float* __restrict__ lw, const float* __restrict__ lb,
    float* __restrict__ out) {
  int idx = blockIdx.x * 256 + threadIdx.x;
  if (idx >= NTOT * D_) return;
  int d = idx & (D_ - 1);
  int r = idx >> 7;
  int t = r & (T_ - 1);
  int bn = r >> 7;
  int n = bn & (NA - 1);
  int b = bn >> 6;
  const float invn = 1.f / (float)(B_ * NN);
  float m = st[0] * invn;
  float var = st[1] * invn - m * m;
  float rs = rsqrtf(var + EPS_);
  float gv = g[(size_t)b * NN + t * NA + n];
  float val = (gv - m) * rs * bng[0] + bnb[0];
  out[idx] = val * lw[d] + lb[d];
}

extern "C" void kernel_launch(void* const* d_in, const int* in_sizes, int n_in,
                              void* d_out, int out_size, void* d_ws, size_t ws_size,
                              hipStream_t stream) {
  const float* hist = (const float*)d_in[0];
  const int* eidx = (const int*)d_in[1];
  const float* ew = (const float*)d_in[2];
  const float* hw = (const float*)d_in[3];
  const float* hb = (const float*)d_in[4];
  const float* wq = (const float*)d_in[5];
  const float* bq = (const float*)d_in[6];
  const float* wk = (const float*)d_in[7];
  const float* bk = (const float*)d_in[8];
  const float* wv = (const float*)d_in[9];
  const float* bv = (const float*)d_in[10];
  const float* wo = (const float*)d_in[11];
  const float* bo = (const float*)d_in[12];
  const float* ln1g = (const float*)d_in[13];
  const float* ln1b = (const float*)d_in[14];
  const float* w1 = (const float*)d_in[15];
  const float* b1 = (const float*)d_in[16];
  const float* w2 = (const float*)d_in[17];
  const float* b2 = (const float*)d_in[18];
  const float* ln2g = (const float*)d_in[19];
  const float* ln2b = (const float*)d_in[20];
  const float* bng = (const float*)d_in[21];
  const float* bnb = (const float*)d_in[22];
  const float* lgw = (const float*)d_in[23];
  const float* lgb = (const float*)d_in[24];
  float* out = (float*)d_out;

  float* ws = (float*)d_ws;
  const size_t NE = NE_;
  float* bx = ws + 0 * NE;
  float* be = ws + 1 * NE;
  float* h1 = ws + 2 * NE;
  float* qkv = ws + 3 * NE;   // 3NE, [row][384]
  float* ffmid = ws + 3 * NE; // 4NE, overlaps dead qkv
  float* bs_ = ws + 7 * NE;
  float* bg_ = bs_ + NTOT;
  float* bst = bg_ + NTOT;
  float* pbias = bst + 2;
  const int LW = 196608;
  __bf16* whiB = (__bf16*)(pbias + L_ * QLD);
  __bf16* wloB = whiB + (size_t)L_ * LW;

  convert_weights<<<(L_ * LW + 255) / 256, 256, 0, stream>>>(
      wq, wk, wv, wo, w1, w2, whiB, wloB);
  bias_pack<<<(L_ * QLD + 255) / 256, 256, 0, stream>>>(bq, bk, bv, pbias);
  embed_kernel<<<(NTOT * D_) / 256, 256, 0, stream>>>(hist, hw, hb, bx, be);

  for (int l = 0; l < L_; ++l) {
    const __bf16* hiL = whiB + (size_t)l * LW;
    const __bf16* loL = wloB + (size_t)l * LW;
    gemm_big<0, 128><<<dim3(3, NTOT / 128), 256, 0, stream>>>(
        be, 128, hiL, loL, pbias + l * QLD, qkv, QLD);
    attn_mfma<<<B_ * NA * H_, 256, 0, stream>>>(qkv);
    // O-proj + resid + LN1 -> h1 (register-gather, r12-proven)
    gemm_ln<128><<<dim3(1, NTOT / 64), 256, 0, stream>>>(
        qkv + 256, QLD, hiL + 49152, loL + 49152, bo + l * D_, be,
        ln1g + l * D_, ln1b + l * D_, h1);
    gemm_big<1, 128><<<dim3(4, NTOT / 128), 256, 0, stream>>>(
        h1, 128, hiL + 65536, loL + 65536, b1 + l * DFF, ffmid, 512);
    // FF2 + resid + LN2 -> be (staged, r12-proven); last layer fuses gating dot
    if (l < L_ - 1) {
      ff2_ln<0><<<dim3(1, NTOT / 64), 256, 0, stream>>>(
          ffmid, hiL + 131072, loL + 131072, b2 + l * D_, h1,
          ln2g + l * D_, ln2b + l * D_, be, nullptr, nullptr);
    } else {
      ff2_ln<1><<<dim3(1, NTOT / 64), 256, 0, stream>>>(
          ffmid, hiL + 131072, loL + 131072, b2 + l * D_, h1,
          ln2g + l * D_, ln2b + l * D_, be, bx, bs_);
    }
  }

  hipMemsetAsync(bg_, 0, ((size_t)B_ * NN + 2) * sizeof(float), stream);
  scatter_kernel<<<(B_ * E_) / 256, 256, 0, stream>>>(bs_, eidx, ew, bg_);
  stats_partial<<<(B_ * NN) / 256, 256, 0, stream>>>(bg_, bst);
  final_kernel<<<(NTOT * D_) / 256, 256, 0, stream>>>(bg_, bst, bng, bnb, lgw, lgb, out);
}

// Round 16
// 537.657 us; speedup vs baseline: 1.1207x; 1.0312x over previous
//
#include <hip/hip_runtime.h>
#include <hip/hip_bf16.h>
#include <math.h>

#define EPS_ 1e-5f
constexpr int B_ = 4, NA = 64, T_ = 128, D_ = 128, H_ = 8, L_ = 3, DFF = 512, E_ = 65536;
constexpr int DH = D_ / H_;        // 16
constexpr int NN = T_ * NA;        // 8192
constexpr int NTOT = B_ * NA * T_; // 32768
constexpr int QLD = 384;           // packed QKV row stride
constexpr size_t NE_ = (size_t)NTOT * D_;

typedef __bf16 bf16x8 __attribute__((ext_vector_type(8)));
typedef float f32x4 __attribute__((ext_vector_type(4)));

// ---------------- embed: x = hist@W + b ; e = x + posenc ----------------
__global__ __launch_bounds__(256) void embed_kernel(
    const float* __restrict__ hist, const float* __restrict__ w,
    const float* __restrict__ b, float* __restrict__ x, float* __restrict__ e) {
  int idx = blockIdx.x * 256 + threadIdx.x;
  if (idx >= NTOT * D_) return;
  int d = idx & (D_ - 1);
  int r = idx >> 7;
  int t = r & (T_ - 1);
  const float* hp = hist + (size_t)r * 3;
  float acc = b[d];
  acc += hp[0] * w[0 * D_ + d];
  acc += hp[1] * w[1 * D_ + d];
  acc += hp[2] * w[2 * D_ + d];
  x[idx] = acc;
  int p = d >> 1;
  float ang = (float)t * expf(-logf(10000.f) * (2.f * (float)p) / (float)D_);
  float pe = (d & 1) ? cosf(ang) : sinf(ang);
  e[idx] = acc + pe;
}

// ---------------- weight split into FRAGMENT-LINEAR bf16 hi/lo ----------------
__global__ __launch_bounds__(256) void convert_weights(
    const float* __restrict__ wq, const float* __restrict__ wk,
    const float* __restrict__ wv, const float* __restrict__ wo,
    const float* __restrict__ w1, const float* __restrict__ w2,
    __bf16* __restrict__ hi, __bf16* __restrict__ lo) {
  const int LW = 196608;
  int idx = blockIdx.x * 256 + threadIdx.x;
  if (idx >= L_ * LW) return;
  int l = idx / LW;
  int rem = idx - l * LW;
  float src;
  int n, k, K, segoff;
  if (rem < 49152) { // qkv
    n = rem >> 7; k = rem & 127; K = 128; segoff = 0;
    int which = n >> 7, nl = n & 127;
    const float* W = (which == 0) ? wq : (which == 1) ? wk : wv;
    src = W[(size_t)l * 16384 + k * 128 + nl];
  } else if (rem < 65536) { // wo
    int r2 = rem - 49152;
    n = r2 >> 7; k = r2 & 127; K = 128; segoff = 49152;
    src = wo[(size_t)l * 16384 + k * 128 + n];
  } else if (rem < 131072) { // w1
    int r2 = rem - 65536;
    n = r2 >> 7; k = r2 & 127; K = 128; segoff = 65536;
    src = w1[(size_t)l * 65536 + k * 512 + n];
  } else { // w2
    int r2 = rem - 131072;
    n = r2 >> 9; k = r2 & 511; K = 512; segoff = 131072;
    src = w2[(size_t)l * 65536 + k * 128 + n];
  }
  int nt = n >> 4, kt = k >> 5;
  int lane = ((k >> 3) & 3) * 16 + (n & 15);
  int j = k & 7;
  int dst = l * LW + segoff + ((nt * (K / 32) + kt) * 64 + lane) * 8 + j;
  __bf16 h = (__bf16)src;
  hi[dst] = h;
  lo[dst] = (__bf16)(src - (float)h);
}

// ---------------- pack QKV biases ----------------
__global__ __launch_bounds__(256) void bias_pack(
    const float* __restrict__ bq, const float* __restrict__ bk,
    const float* __restrict__ bv, float* __restrict__ pb) {
  int idx = blockIdx.x * 256 + threadIdx.x;
  if (idx >= L_ * QLD) return;
  int l = idx / QLD, n = idx - l * QLD;
  int which = n >> 7, nl = n & 127;
  const float* src = (which == 0) ? bq : (which == 1) ? bk : bv;
  pb[idx] = src[l * 128 + nl];
}

__device__ __forceinline__ void split8(const float* __restrict__ p,
                                       bf16x8& hi, bf16x8& lo) {
  float4 x0 = *(const float4*)p;
  float4 x1 = *(const float4*)(p + 4);
  float xv[8] = {x0.x, x0.y, x0.z, x0.w, x1.x, x1.y, x1.z, x1.w};
#pragma unroll
  for (int j = 0; j < 8; ++j) {
    __bf16 h = (__bf16)xv[j];
    hi[j] = h;
    lo[j] = (__bf16)(xv[j] - (float)h);
  }
}

// ---------------- MFMA GEMM, 128x128 tile (wave 64x64), frag-linear W [r12] ----------------
template <int EPI, int K>
__global__ __launch_bounds__(256) void gemm_big(
    const float* __restrict__ A, int lda,
    const __bf16* __restrict__ Whi, const __bf16* __restrict__ Wlo,
    const float* __restrict__ bias,
    float* __restrict__ C, int ldc) {
  const int wave = threadIdx.x >> 6;
  const int lane = threadIdx.x & 63;
  const int m16 = lane & 15;
  const int quad = lane >> 4;
  const int wrow = wave >> 1, wcol = wave & 1;
  const int row0 = blockIdx.y * 128 + wrow * 64;
  const int col0 = blockIdx.x * 128 + wcol * 64;
  const int ctb = col0 >> 4;

  f32x4 acc[4][4] = {};
#pragma unroll
  for (int k0 = 0; k0 < K; k0 += 32) {
    bf16x8 ahi[4], alo[4];
#pragma unroll
    for (int mf = 0; mf < 4; ++mf)
      split8(A + (size_t)(row0 + mf * 16 + m16) * lda + k0 + quad * 8, ahi[mf], alo[mf]);
    bf16x8 bhi[4], blo[4];
#pragma unroll
    for (int nf = 0; nf < 4; ++nf) {
      size_t off = ((size_t)(ctb + nf) * (K / 32) + (k0 >> 5)) * 512 + lane * 8;
      bhi[nf] = *(const bf16x8*)(Whi + off);
      blo[nf] = *(const bf16x8*)(Wlo + off);
    }
#pragma unroll
    for (int mf = 0; mf < 4; ++mf)
#pragma unroll
      for (int nf = 0; nf < 4; ++nf) {
        acc[mf][nf] = __builtin_amdgcn_mfma_f32_16x16x32_bf16(ahi[mf], bhi[nf], acc[mf][nf], 0, 0, 0);
        acc[mf][nf] = __builtin_amdgcn_mfma_f32_16x16x32_bf16(ahi[mf], blo[nf], acc[mf][nf], 0, 0, 0);
        acc[mf][nf] = __builtin_amdgcn_mfma_f32_16x16x32_bf16(alo[mf], bhi[nf], acc[mf][nf], 0, 0, 0);
      }
  }
#pragma unroll
  for (int mf = 0; mf < 4; ++mf)
#pragma unroll
    for (int nf = 0; nf < 4; ++nf) {
      int c = col0 + nf * 16 + m16;
      float bj = bias[c];
#pragma unroll
      for (int reg = 0; reg < 4; ++reg) {
        int r = row0 + mf * 16 + quad * 4 + reg;
        float v = acc[mf][nf][reg] + bj;
        if (EPI == 1) v = fmaxf(v, 0.f);
        C[(size_t)r * ldc + c] = v;
      }
    }
}

// ---------------- GEMM + bias + resid + LayerNorm; block 64x128, register A [r12] ----------------
template <int K>
__global__ __launch_bounds__(256) void gemm_ln(
    const float* __restrict__ A, int lda,
    const __bf16* __restrict__ Whi, const __bf16* __restrict__ Wlo,
    const float* __restrict__ bias, const float* __restrict__ resid,
    const float* __restrict__ lng, const float* __restrict__ lnb,
    float* __restrict__ C) {
  const int wave = threadIdx.x >> 6;
  const int lane = threadIdx.x & 63;
  const int m16 = lane & 15;
  const int quad = lane >> 4;
  const int wrow = wave >> 1, wcol = wave & 1;
  const int row0 = blockIdx.y * 64 + wrow * 32;
  const int col0 = wcol * 64;
  const int ctb = wcol * 4;

  f32x4 acc[2][4] = {};
#pragma unroll
  for (int k0 = 0; k0 < K; k0 += 32) {
    bf16x8 ahi[2], alo[2];
#pragma unroll
    for (int mf = 0; mf < 2; ++mf)
      split8(A + (size_t)(row0 + mf * 16 + m16) * lda + k0 + quad * 8, ahi[mf], alo[mf]);
    bf16x8 bhi[4], blo[4];
#pragma unroll
    for (int nf = 0; nf < 4; ++nf) {
      size_t off = ((size_t)(ctb + nf) * (K / 32) + (k0 >> 5)) * 512 + lane * 8;
      bhi[nf] = *(const bf16x8*)(Whi + off);
      blo[nf] = *(const bf16x8*)(Wlo + off);
    }
#pragma unroll
    for (int mf = 0; mf < 2; ++mf)
#pragma unroll
      for (int nf = 0; nf < 4; ++nf) {
        acc[mf][nf] = __builtin_amdgcn_mfma_f32_16x16x32_bf16(ahi[mf], bhi[nf], acc[mf][nf], 0, 0, 0);
        acc[mf][nf] = __builtin_amdgcn_mfma_f32_16x16x32_bf16(ahi[mf], blo[nf], acc[mf][nf], 0, 0, 0);
        acc[mf][nf] = __builtin_amdgcn_mfma_f32_16x16x32_bf16(alo[mf], bhi[nf], acc[mf][nf], 0, 0, 0);
      }
  }
  __shared__ float rs[64][2], rq[64][2];
#pragma unroll
  for (int mf = 0; mf < 2; ++mf)
#pragma unroll
    for (int reg = 0; reg < 4; ++reg) {
      int lr = wrow * 32 + mf * 16 + quad * 4 + reg;
      int gr = blockIdx.y * 64 + lr;
      float s = 0.f, qq = 0.f;
#pragma unroll
      for (int nf = 0; nf < 4; ++nf) {
        int c = col0 + nf * 16 + m16;
        float v = acc[mf][nf][reg] + bias[c] + resid[(size_t)gr * 128 + c];
        acc[mf][nf][reg] = v;
        s += v;
        qq += v * v;
      }
#pragma unroll
      for (int off = 1; off < 16; off <<= 1) {
        s += __shfl_xor(s, off, 64);
        qq += __shfl_xor(qq, off, 64);
      }
      if (m16 == 0) { rs[lr][wcol] = s; rq[lr][wcol] = qq; }
    }
  __syncthreads();
#pragma unroll
  for (int mf = 0; mf < 2; ++mf)
#pragma unroll
    for (int reg = 0; reg < 4; ++reg) {
      int lr = wrow * 32 + mf * 16 + quad * 4 + reg;
      int gr = blockIdx.y * 64 + lr;
      float mean = (rs[lr][0] + rs[lr][1]) * (1.f / 128.f);
      float var = (rq[lr][0] + rq[lr][1]) * (1.f / 128.f) - mean * mean;
      float rstd = rsqrtf(var + EPS_);
#pragma unroll
      for (int nf = 0; nf < 4; ++nf) {
        int c = col0 + nf * 16 + m16;
        C[(size_t)gr * 128 + c] = (acc[mf][nf][reg] - mean) * rstd * lng[c] + lnb[c];
      }
    }
}

// ---------------- FF2 + LN (staged A, K=512) [r12]; SDOT fuses gating dot [r15] ----------------
template <int SDOT>
__global__ __launch_bounds__(256) void ff2_ln(
    const float* __restrict__ A, // ffmid [M][512]
    const __bf16* __restrict__ Whi, const __bf16* __restrict__ Wlo,
    const float* __restrict__ bias, const float* __restrict__ resid,
    const float* __restrict__ lng, const float* __restrict__ lnb,
    float* __restrict__ C,
    const float* __restrict__ bx, float* __restrict__ sdst) {
  const int wave = threadIdx.x >> 6;
  const int lane = threadIdx.x & 63;
  const int m16 = lane & 15;
  const int quad = lane >> 4;
  const int wrow = wave >> 1, wcol = wave & 1;
  const int grow0 = blockIdx.y * 64;
  const int lrow0 = wrow * 32;
  const int col0 = wcol * 64;
  const int ctb = wcol * 4;

  __shared__ float As[64][129];

  f32x4 acc[2][4] = {};
  for (int kc = 0; kc < 4; ++kc) {
    if (kc) __syncthreads();
#pragma unroll
    for (int u = 0; u < 8; ++u) {
      int unit = threadIdx.x + u * 256;
      int r = unit >> 5, c4 = unit & 31;
      float4 v = *(const float4*)(A + (size_t)(grow0 + r) * 512 + kc * 128 + c4 * 4);
      As[r][c4 * 4 + 0] = v.x;
      As[r][c4 * 4 + 1] = v.y;
      As[r][c4 * 4 + 2] = v.z;
      As[r][c4 * 4 + 3] = v.w;
    }
    __syncthreads();
#pragma unroll
    for (int kt = 0; kt < 4; ++kt) {
      bf16x8 ahi[2], alo[2];
#pragma unroll
      for (int mf = 0; mf < 2; ++mf)
        split8(&As[lrow0 + mf * 16 + m16][kt * 32 + quad * 8], ahi[mf], alo[mf]);
      bf16x8 bhi[4], blo[4];
#pragma unroll
      for (int nf = 0; nf < 4; ++nf) {
        size_t off = ((size_t)(ctb + nf) * 16 + (kc * 4 + kt)) * 512 + lane * 8;
        bhi[nf] = *(const bf16x8*)(Whi + off);
        blo[nf] = *(const bf16x8*)(Wlo + off);
      }
#pragma unroll
      for (int mf = 0; mf < 2; ++mf)
#pragma unroll
        for (int nf = 0; nf < 4; ++nf) {
          acc[mf][nf] = __builtin_amdgcn_mfma_f32_16x16x32_bf16(ahi[mf], bhi[nf], acc[mf][nf], 0, 0, 0);
          acc[mf][nf] = __builtin_amdgcn_mfma_f32_16x16x32_bf16(ahi[mf], blo[nf], acc[mf][nf], 0, 0, 0);
          acc[mf][nf] = __builtin_amdgcn_mfma_f32_16x16x32_bf16(alo[mf], bhi[nf], acc[mf][nf], 0, 0, 0);
        }
    }
  }
  __shared__ float rs[64][2], rq[64][2];
  __shared__ float sd[64][2];
#pragma unroll
  for (int mf = 0; mf < 2; ++mf)
#pragma unroll
    for (int reg = 0; reg < 4; ++reg) {
      int lr = lrow0 + mf * 16 + quad * 4 + reg;
      int gr = grow0 + lr;
      float s = 0.f, qq = 0.f;
#pragma unroll
      for (int nf = 0; nf < 4; ++nf) {
        int c = col0 + nf * 16 + m16;
        float v = acc[mf][nf][reg] + bias[c] + resid[(size_t)gr * 128 + c];
        acc[mf][nf][reg] = v;
        s += v;
        qq += v * v;
      }
#pragma unroll
      for (int off = 1; off < 16; off <<= 1) {
        s += __shfl_xor(s, off, 64);
        qq += __shfl_xor(qq, off, 64);
      }
      if (m16 == 0) { rs[lr][wcol] = s; rq[lr][wcol] = qq; }
    }
  __syncthreads();
#pragma unroll
  for (int mf = 0; mf < 2; ++mf)
#pragma unroll
    for (int reg = 0; reg < 4; ++reg) {
      int lr = lrow0 + mf * 16 + quad * 4 + reg;
      int gr = grow0 + lr;
      float mean = (rs[lr][0] + rs[lr][1]) * (1.f / 128.f);
      float var = (rq[lr][0] + rq[lr][1]) * (1.f / 128.f) - mean * mean;
      float rstd = rsqrtf(var + EPS_);
      float sdp = 0.f;
#pragma unroll
      for (int nf = 0; nf < 4; ++nf) {
        int c = col0 + nf * 16 + m16;
        float v = (acc[mf][nf][reg] - mean) * rstd * lng[c] + lnb[c];
        C[(size_t)gr * 128 + c] = v;
        if (SDOT) sdp += v * bx[(size_t)gr * 128 + c];
      }
      if (SDOT) {
#pragma unroll
        for (int off = 1; off < 16; off <<= 1) sdp += __shfl_xor(sdp, off, 64);
        if (m16 == 0) sd[lr][wcol] = sdp;
      }
    }
  if (SDOT) {
    __syncthreads();
    if (threadIdx.x < 64) {
      int lr = threadIdx.x;
      int gr = grow0 + lr;
      float sv = sd[lr][0] + sd[lr][1];
      int t = gr & (T_ - 1);
      int bn = gr >> 7;
      int n = bn & (NA - 1);
      int b = bn >> 6;
      sdst[(size_t)b * NN + t * NA + n] = sv;
    }
  }
}

// ---------------- MFMA attention v2: K/V staged once per block in frag-linear LDS ----------------
__global__ __launch_bounds__(256) void attn_mfma(float* __restrict__ qkv) {
  const int h = blockIdx.x & (H_ - 1);
  const int bn = blockIdx.x >> 3;
  const int wave = threadIdx.x >> 6;
  const int lane = threadIdx.x & 63;
  const int m16 = lane & 15;
  const int quad = lane >> 4;
  const int row0 = wave * 32;
  const float* Qb = qkv + (size_t)bn * T_ * QLD + h * DH;
  const float* Kb = Qb + 128;
  const float* Vb = Qb + 256;
  float* Ob = (float*)Vb;

  __shared__ __bf16 Plds[4][32][136];
  __shared__ __bf16 KH[8][32][8], KL[8][32][8]; // K frag-linear: [nf][quad*16+t15][dh&7]
  __shared__ __bf16 VH[4][64][8], VL[4][64][8]; // V frag-linear: [kc][kq*16+dh][t&7]

  // cooperative stage: K and V (128 rows x 16 dh each), coalesced float4, hi/lo split
  for (int u = threadIdx.x; u < 1024; u += 256) {
    int isV = u >> 9;
    int r2 = u & 511;
    int t = r2 >> 2, c4 = r2 & 3;
    float4 v = *(const float4*)((isV ? Vb : Kb) + (size_t)t * QLD + c4 * 4);
    float xv[4] = {v.x, v.y, v.z, v.w};
#pragma unroll
    for (int i = 0; i < 4; ++i) {
      int dh = c4 * 4 + i;
      __bf16 hh = (__bf16)xv[i];
      __bf16 ll = (__bf16)(xv[i] - (float)hh);
      if (isV) {
        int kc = t >> 5, rem = t & 31;
        int vl = (rem >> 3) * 16 + dh;
        VH[kc][vl][rem & 7] = hh;
        VL[kc][vl][rem & 7] = ll;
      } else {
        int nf = t >> 4;
        int kl = (dh >> 3) * 16 + (t & 15);
        KH[nf][kl][dh & 7] = hh;
        KL[nf][kl][dh & 7] = ll;
      }
    }
  }

  // Q A-frags from global (registers, zero-pad quad>=2)
  bf16x8 qhi[2], qlo[2];
#pragma unroll
  for (int mf = 0; mf < 2; ++mf) {
    if (quad < 2) {
      split8(Qb + (size_t)(row0 + mf * 16 + m16) * QLD + quad * 8, qhi[mf], qlo[mf]);
    } else {
#pragma unroll
      for (int j = 0; j < 8; ++j) { qhi[mf][j] = (__bf16)0.f; qlo[mf][j] = (__bf16)0.f; }
    }
  }
  __syncthreads(); // staging complete

  f32x4 acc[2][8] = {};
#pragma unroll
  for (int nf = 0; nf < 8; ++nf) {
    bf16x8 khi, klo;
    if (quad < 2) {
      khi = *(const bf16x8*)&KH[nf][lane][0]; // lane in [0,32)
      klo = *(const bf16x8*)&KL[nf][lane][0];
    } else {
#pragma unroll
      for (int j = 0; j < 8; ++j) { khi[j] = (__bf16)0.f; klo[j] = (__bf16)0.f; }
    }
#pragma unroll
    for (int mf = 0; mf < 2; ++mf) {
      acc[mf][nf] = __builtin_amdgcn_mfma_f32_16x16x32_bf16(qhi[mf], khi, acc[mf][nf], 0, 0, 0);
      acc[mf][nf] = __builtin_amdgcn_mfma_f32_16x16x32_bf16(qhi[mf], klo, acc[mf][nf], 0, 0, 0);
      acc[mf][nf] = __builtin_amdgcn_mfma_f32_16x16x32_bf16(qlo[mf], khi, acc[mf][nf], 0, 0, 0);
    }
  }

  const float scale = 0.25f;
#pragma unroll
  for (int mf = 0; mf < 2; ++mf)
#pragma unroll
    for (int reg = 0; reg < 4; ++reg) {
      float mx = -1e30f;
#pragma unroll
      for (int nf = 0; nf < 8; ++nf) mx = fmaxf(mx, acc[mf][nf][reg]);
#pragma unroll
      for (int off = 1; off < 16; off <<= 1) mx = fmaxf(mx, __shfl_xor(mx, off, 64));
      float sum = 0.f;
#pragma unroll
      for (int nf = 0; nf < 8; ++nf) {
        float e = __expf((acc[mf][nf][reg] - mx) * scale);
        acc[mf][nf][reg] = e;
        sum += e;
      }
#pragma unroll
      for (int off = 1; off < 16; off <<= 1) sum += __shfl_xor(sum, off, 64);
      float inv = 1.f / sum;
#pragma unroll
      for (int nf = 0; nf < 8; ++nf) acc[mf][nf][reg] *= inv;
    }

#pragma unroll
  for (int mf = 0; mf < 2; ++mf)
#pragma unroll
    for (int nf = 0; nf < 8; ++nf)
#pragma unroll
      for (int reg = 0; reg < 4; ++reg)
        Plds[wave][mf * 16 + quad * 4 + reg][nf * 16 + m16] = (__bf16)acc[mf][nf][reg];

  f32x4 oacc[2] = {};
#pragma unroll
  for (int kc = 0; kc < 4; ++kc) {
    bf16x8 pa0 = *(const bf16x8*)&Plds[wave][m16][kc * 32 + quad * 8];
    bf16x8 pa1 = *(const bf16x8*)&Plds[wave][16 + m16][kc * 32 + quad * 8];
    bf16x8 vhi = *(const bf16x8*)&VH[kc][lane][0];
    bf16x8 vlo = *(const bf16x8*)&VL[kc][lane][0];
    oacc[0] = __builtin_amdgcn_mfma_f32_16x16x32_bf16(pa0, vhi, oacc[0], 0, 0, 0);
    oacc[0] = __builtin_amdgcn_mfma_f32_16x16x32_bf16(pa0, vlo, oacc[0], 0, 0, 0);
    oacc[1] = __builtin_amdgcn_mfma_f32_16x16x32_bf16(pa1, vhi, oacc[1], 0, 0, 0);
    oacc[1] = __builtin_amdgcn_mfma_f32_16x16x32_bf16(pa1, vlo, oacc[1], 0, 0, 0);
  }

  // Global V slice was consumed during staging (before the barrier) — O write is safe.
#pragma unroll
  for (int mf = 0; mf < 2; ++mf)
#pragma unroll
    for (int reg = 0; reg < 4; ++reg) {
      int r = row0 + mf * 16 + quad * 4 + reg;
      Ob[(size_t)r * QLD + m16] = oacc[mf][reg];
    }
}

// ---------------- edge scatter ----------------
__global__ __launch_bounds__(256) void scatter_kernel(
    const float* __restrict__ s, const int* __restrict__ ei,
    const float* __restrict__ ew, float* __restrict__ g) {
  int idx = blockIdx.x * 256 + threadIdx.x;
  if (idx >= B_ * E_) return;
  int b = idx >> 16;
  int e = idx & (E_ - 1);
  int src = ei[(size_t)b * 2 * E_ + e];
  int dst = ei[(size_t)b * 2 * E_ + E_ + e];
  float w = ew[(size_t)b * E_ + e];
  atomicAdd(&g[(size_t)b * NN + dst], w * s[(size_t)b * NN + src]);
}

// ---------------- partial sums for global mean/var ----------------
__global__ __launch_bounds__(256) void stats_partial(
    const float* __restrict__ g, float* __restrict__ st) {
  int i = blockIdx.x * 256 + threadIdx.x;
  float v = g[i];
  float sum = v, sq = v * v;
#pragma unroll
  for (int off = 32; off; off >>= 1) {
    sum += __shfl_down(sum, off, 64);
    sq += __shfl_down(sq, off, 64);
  }
  __shared__ float s1[4], s2[4];
  int w = threadIdx.x >> 6;
  if ((threadIdx.x & 63) == 0) { s1[w] = sum; s2[w] = sq; }
  __syncthreads();
  if (threadIdx.x == 0) {
    atomicAdd(&st[0], s1[0] + s1[1] + s1[2] + s1[3]);
    atomicAdd(&st[1], s2[0] + s2[1] + s2[2] + s2[3]);
  }
}

// ---------------- final (fp32 out) ----------------
__global__ __launch_bounds__(256) void final_kernel(
    const float* __restrict__ g, const float* __restrict__ st,
    const float* __restrict__ bng, const float* __restrict__ bnb,
    const float* __restrict__ lw, const float* __restrict__ lb,
    float* __restrict__ out) {
  int idx = blockIdx.x * 256 + threadIdx.x;
  if (idx >= NTOT * D_) return;
  int d = idx & (D_ - 1);
  int r = idx >> 7;
  int t = r & (T_ - 1);
  int bn = r >> 7;
  int n = bn & (NA - 1);
  int b = bn >> 6;
  const float invn = 1.f / (float)(B_ * NN);
  float m = st[0] * invn;
  float var = st[1] * invn - m * m;
  float rs = rsqrtf(var + EPS_);
  float gv = g[(size_t)b * NN + t * NA + n];
  float val = (gv - m) * rs * bng[0] + bnb[0];
  out[idx] = val * lw[d] + lb[d];
}

extern "C" void kernel_launch(void* const* d_in, const int* in_sizes, int n_in,
                              void* d_out, int out_size, void* d_ws, size_t ws_size,
                              hipStream_t stream) {
  const float* hist = (const float*)d_in[0];
  const int* eidx = (const int*)d_in[1];
  const float* ew = (const float*)d_in[2];
  const float* hw = (const float*)d_in[3];
  const float* hb = (const float*)d_in[4];
  const float* wq = (const float*)d_in[5];
  const float* bq = (const float*)d_in[6];
  const float* wk = (const float*)d_in[7];
  const float* bk = (const float*)d_in[8];
  const float* wv = (const float*)d_in[9];
  const float* bv = (const float*)d_in[10];
  const float* wo = (const float*)d_in[11];
  const float* bo = (const float*)d_in[12];
  const float* ln1g = (const float*)d_in[13];
  const float* ln1b = (const float*)d_in[14];
  const float* w1 = (const float*)d_in[15];
  const float* b1 = (const float*)d_in[16];
  const float* w2 = (const float*)d_in[17];
  const float* b2 = (const float*)d_in[18];
  const float* ln2g = (const float*)d_in[19];
  const float* ln2b = (const float*)d_in[20];
  const float* bng = (const float*)d_in[21];
  const float* bnb = (const float*)d_in[22];
  const float* lgw = (const float*)d_in[23];
  const float* lgb = (const float*)d_in[24];
  float* out = (float*)d_out;

  float* ws = (float*)d_ws;
  const size_t NE = NE_;
  float* bx = ws + 0 * NE;
  float* be = ws + 1 * NE;
  float* h1 = ws + 2 * NE;
  float* qkv = ws + 3 * NE;   // 3NE, [row][384]
  float* ffmid = ws + 3 * NE; // 4NE, overlaps dead qkv
  float* bs_ = ws + 7 * NE;
  float* bg_ = bs_ + NTOT;
  float* bst = bg_ + NTOT;
  float* pbias = bst + 2;
  const int LW = 196608;
  __bf16* whiB = (__bf16*)(pbias + L_ * QLD);
  __bf16* wloB = whiB + (size_t)L_ * LW;

  convert_weights<<<(L_ * LW + 255) / 256, 256, 0, stream>>>(
      wq, wk, wv, wo, w1, w2, whiB, wloB);
  bias_pack<<<(L_ * QLD + 255) / 256, 256, 0, stream>>>(bq, bk, bv, pbias);
  embed_kernel<<<(NTOT * D_) / 256, 256, 0, stream>>>(hist, hw, hb, bx, be);

  for (int l = 0; l < L_; ++l) {
    const __bf16* hiL = whiB + (size_t)l * LW;
    const __bf16* loL = wloB + (size_t)l * LW;
    gemm_big<0, 128><<<dim3(3, NTOT / 128), 256, 0, stream>>>(
        be, 128, hiL, loL, pbias + l * QLD, qkv, QLD);
    attn_mfma<<<B_ * NA * H_, 256, 0, stream>>>(qkv);
    gemm_ln<128><<<dim3(1, NTOT / 64), 256, 0, stream>>>(
        qkv + 256, QLD, hiL + 49152, loL + 49152, bo + l * D_, be,
        ln1g + l * D_, ln1b + l * D_, h1);
    gemm_big<1, 128><<<dim3(4, NTOT / 128), 256, 0, stream>>>(
        h1, 128, hiL + 65536, loL + 65536, b1 + l * DFF, ffmid, 512);
    if (l < L_ - 1) {
      ff2_ln<0><<<dim3(1, NTOT / 64), 256, 0, stream>>>(
          ffmid, hiL + 131072, loL + 131072, b2 + l * D_, h1,
          ln2g + l * D_, ln2b + l * D_, be, nullptr, nullptr);
    } else {
      ff2_ln<1><<<dim3(1, NTOT / 64), 256, 0, stream>>>(
          ffmid, hiL + 131072, loL + 131072, b2 + l * D_, h1,
          ln2g + l * D_, ln2b + l * D_, be, bx, bs_);
    }
  }

  hipMemsetAsync(bg_, 0, ((size_t)B_ * NN + 2) * sizeof(float), stream);
  scatter_kernel<<<(B_ * E_) / 256, 256, 0, stream>>>(bs_, eidx, ew, bg_);
  stats_partial<<<(B_ * NN) / 256, 256, 0, stream>>>(bg_, bst);
  final_kernel<<<(NTOT * D_) / 256, 256, 0, stream>>>(bg_, bst, bng, bnb, lgw, lgb, out);
}